// Round 6
// baseline (515.747 us; speedup 1.0000x reference)
//
#include <hip/hip_runtime.h>
#include <cstdint>
#include <cstddef>

// Problem constants
#define BDIM 2
#define NTOK 4096
#define EDIM 1024
#define HEADS 16
#define HDIM 64
#define MROWS (BDIM * NTOK)   // 8192

typedef unsigned short u16;
typedef __attribute__((ext_vector_type(8))) short bf16x8;   // 8 bf16 = 4 VGPR
typedef __attribute__((ext_vector_type(8))) unsigned short u16x8;
typedef __attribute__((ext_vector_type(4))) float f32x4;

#define MFMA(a, b, c) __builtin_amdgcn_mfma_f32_16x16x32_bf16(a, b, c, 0, 0, 0)
#define BAR() asm volatile("s_barrier" ::: "memory")
#define SETPRIO(p) __builtin_amdgcn_s_setprio(p)

// round-to-nearest-even split of fp32 into hi/lo bf16
__device__ inline void split2(float x, u16& h, u16& l) {
    union { float f; unsigned u; } a;
    a.f = x;
    unsigned uh = a.u + 0x7fff + ((a.u >> 16) & 1);
    h = (u16)(uh >> 16);
    union { unsigned u; float f; } hf; hf.u = (unsigned)h << 16;
    a.f = x - hf.f;
    unsigned ul = a.u + 0x7fff + ((a.u >> 16) & 1);
    l = (u16)(ul >> 16);
}

__device__ inline u16 bf16rne(float x) {
    union { float f; unsigned u; } a; a.f = x;
    unsigned r = a.u + 0x7fff + ((a.u >> 16) & 1);
    return (u16)(r >> 16);
}

// global -> LDS direct 16B staging (lane i lands at lds_base + i*16)
#define GLL(gp, lp) __builtin_amdgcn_global_load_lds( \
    (const __attribute__((address_space(1))) unsigned*)(gp), \
    (__attribute__((address_space(3))) unsigned*)(lp), 16, 0, 0)

// ---------------------------------------------------------------------------
// W_eff = W + 2*B@A for all 4 projections in one launch. grid=(4096,4)
// ---------------------------------------------------------------------------
__global__ __launch_bounds__(256) void build_weff4_kernel(
    const float* __restrict__ W0, const float* __restrict__ A0, const float* __restrict__ B0,
    const float* __restrict__ W1, const float* __restrict__ A1, const float* __restrict__ B1,
    const float* __restrict__ W2, const float* __restrict__ A2, const float* __restrict__ B2,
    const float* __restrict__ W3, const float* __restrict__ A3, const float* __restrict__ B3,
    u16* __restrict__ dh0, u16* __restrict__ dl0,
    u16* __restrict__ dh1, u16* __restrict__ dl1,
    u16* __restrict__ dh2, u16* __restrict__ dl2,
    u16* __restrict__ dh3, u16* __restrict__ dl3)
{
    int s = blockIdx.y;
    const float* W = (s == 0) ? W0 : (s == 1) ? W1 : (s == 2) ? W2 : W3;
    const float* A = (s == 0) ? A0 : (s == 1) ? A1 : (s == 2) ? A2 : A3;
    const float* Bm = (s == 0) ? B0 : (s == 1) ? B1 : (s == 2) ? B2 : B3;
    u16* dh = (s == 0) ? dh0 : (s == 1) ? dh1 : (s == 2) ? dh2 : dh3;
    u16* dl = (s == 0) ? dl0 : (s == 1) ? dl1 : (s == 2) ? dl2 : dl3;

    int idx = blockIdx.x * 256 + threadIdx.x;      // over E*E
    int o = idx >> 10, i = idx & 1023;
    float sum = 0.f;
#pragma unroll
    for (int r = 0; r < 8; ++r) sum += Bm[o * 8 + r] * A[r * 1024 + i];
    float w = W[idx] + 2.0f * sum;
    u16 h, l;
    split2(w, h, l);
    dh[idx] = h; dl[idx] = l;
}

// ---------------------------------------------------------------------------
// fp32 buffer -> hi/lo bf16 buffers, 4 elements / thread
// ---------------------------------------------------------------------------
__global__ __launch_bounds__(256) void split_kernel(
    const float* __restrict__ src, u16* __restrict__ dh, u16* __restrict__ dl)
{
    int idx = blockIdx.x * 256 + threadIdx.x;      // one float4
    float4 v = ((const float4*)src)[idx];
    ushort4 h, l;
    split2(v.x, h.x, l.x);
    split2(v.y, h.y, l.y);
    split2(v.z, h.z, l.z);
    split2(v.w, h.w, l.w);
    ((ushort4*)dh)[idx] = h;
    ((ushort4*)dl)[idx] = l;
}

// ---------------------------------------------------------------------------
// Parallel stable counting sort, 3 scales x BDIM batches. grid=(BDIM,3).
// ---------------------------------------------------------------------------
__global__ __launch_bounds__(256) void sort3_kernel(
    const int* __restrict__ w0, const int* __restrict__ w1,
    const int* __restrict__ w2, int* __restrict__ sidx)
{
    __shared__ int sb[NTOK];          // 16 KB
    __shared__ int cnt[32][256];      // 32 KB
    __shared__ int gb[256];           // 1 KB
    const int* srcs[3] = {w0, w1, w2};
    int t = threadIdx.x;
    const int* w = srcs[blockIdx.y] + blockIdx.x * NTOK;
    int* outp = sidx + ((int)blockIdx.y * BDIM + (int)blockIdx.x) * NTOK;

    for (int i = t; i < NTOK; i += 256) sb[i] = w[i];
    for (int i = t; i < 32 * 256; i += 256) ((int*)cnt)[i] = 0;
    __syncthreads();

    int g = t >> 3;
#pragma unroll
    for (int e = 0; e < 16; ++e)
        atomicAdd(&cnt[g][sb[g * 128 + (t & 7) + 8 * e]], 1);
    __syncthreads();

    int run = 0;
#pragma unroll
    for (int gg = 0; gg < 32; ++gg) {
        int c = cnt[gg][t];
        cnt[gg][t] = run;
        run += c;
    }
    gb[t] = run;
    __syncthreads();
    if (t == 0) {
        int acc = 0;
        for (int v = 0; v < 256; ++v) { int c = gb[v]; gb[v] = acc; acc += c; }
    }
    __syncthreads();
    for (int i = t; i < 32 * 256; i += 256) {
        int v = i & 255, gg = i >> 8;
        cnt[gg][v] += gb[v];
    }
    __syncthreads();

    if (t < 32) {
        int base = t * 128;
        for (int e = 0; e < 128; ++e) {
            int v = sb[base + e];
            int p = cnt[t][v]++;
            outp[p] = base + e;
        }
    }
}

// ---------------------------------------------------------------------------
// QK split-bf16 MFMA GEMM (3-pass). BM=256, BN=128, BK=32, 512 thr
// (8 waves of 64x64), 3 LDS buffers + counted vmcnt(6).
// ONE barrier per K-step: within a K-step the read buffer is immutable and
// GLLs target a third buffer -> no intra-step hazard; compiler free-schedules
// the 24 ds_reads against the 36 MFMAs. grid = 512.
// ---------------------------------------------------------------------------
__global__ __launch_bounds__(512, 2) void gemm_qk_kernel(
    const u16* __restrict__ Xh, const u16* __restrict__ Xl,
    const u16* __restrict__ Wh, const u16* __restrict__ Wl,
    const float* __restrict__ bq, const float* __restrict__ bk,
    u16* __restrict__ qh, u16* __restrict__ ql,
    u16* __restrict__ kh, u16* __restrict__ kl)
{
    __shared__ __align__(16) unsigned char smem[147456];  // 3 x 48 KB buffers
    u16* lds = (u16*)smem;
    const int PA_h = 0, PA_l = 8192, PB_h = 16384, PB_l = 20480;  // u16 units

    int t = threadIdx.x;
    int lane = t & 63, wave = t >> 6;
    int bid = blockIdx.x;
    int wg = (bid & 7) * 64 + (bid >> 3);   // XCD-bijective swizzle (512%8==0)
    int bx = wg & 15, by = wg >> 4;
    int m0 = by * 256, n0 = bx * 128;       // n0 in [0,2048)

    int lrow = lane & 15, lq = lane >> 4;
    size_t aoff = (size_t)(m0 + wave * 32 + lrow) * EDIM + lq * 8;
    size_t boff = (size_t)(n0 + wave * 16 + lrow) * EDIM + lq * 8;
    int slabA = wave * 2;
    int sA0 = (wave >> 1) * 4;
    int sB0 = (wave & 1) * 4;
    f32x4 acc[4][4] = {};

    // prologue: stage tiles 0 and 1
#pragma unroll
    for (int tt = 0; tt < 2; ++tt) {
        u16* sbuf = lds + tt * 24576;
        int kk = tt * 32;
        GLL(Xh + aoff + kk,             sbuf + PA_h + (slabA + 0) * 512);
        GLL(Xh + aoff + kk + 16 * EDIM, sbuf + PA_h + (slabA + 1) * 512);
        GLL(Xl + aoff + kk,             sbuf + PA_l + (slabA + 0) * 512);
        GLL(Xl + aoff + kk + 16 * EDIM, sbuf + PA_l + (slabA + 1) * 512);
        GLL(Wh + boff + kk, sbuf + PB_h + wave * 512);
        GLL(Wl + boff + kk, sbuf + PB_l + wave * 512);
    }
    asm volatile("s_waitcnt vmcnt(6)" ::: "memory");
    BAR();

    for (int t32 = 0; t32 < 32; ++t32) {
        u16* rb = lds + (t32 % 3) * 24576;
        u16* sbuf = lds + ((t32 + 2) % 3) * 24576;
        bool pf = (t32 + 2) < 32;
        int kn = (t32 + 2) * 32;

        // issue prefetch for t+2 (drained at end of NEXT step via vmcnt(6))
        if (pf) {
            GLL(Xh + aoff + kn,             sbuf + PA_h + (slabA + 0) * 512);
            GLL(Xh + aoff + kn + 16 * EDIM, sbuf + PA_h + (slabA + 1) * 512);
            GLL(Xl + aoff + kn,             sbuf + PA_l + (slabA + 0) * 512);
            GLL(Xl + aoff + kn + 16 * EDIM, sbuf + PA_l + (slabA + 1) * 512);
            GLL(Wh + boff + kn, sbuf + PB_h + wave * 512);
            GLL(Wl + boff + kn, sbuf + PB_l + wave * 512);
        }

        bf16x8 bhf[4], blf[4], aph[4], apl[4];
#pragma unroll
        for (int j = 0; j < 4; ++j) {
            bhf[j] = *(const bf16x8*)(rb + PB_h + (sB0 + j) * 512 + lane * 8);
            blf[j] = *(const bf16x8*)(rb + PB_l + (sB0 + j) * 512 + lane * 8);
        }
#pragma unroll
        for (int p = 0; p < 4; ++p) {
            aph[p] = *(const bf16x8*)(rb + PA_h + (sA0 + p) * 512 + lane * 8);
            apl[p] = *(const bf16x8*)(rb + PA_l + (sA0 + p) * 512 + lane * 8);
        }

        SETPRIO(1);
#pragma unroll
        for (int p = 0; p < 4; ++p)
#pragma unroll
            for (int j = 0; j < 4; ++j) {
                acc[p][j] = MFMA(aph[p], bhf[j], acc[p][j]);
                acc[p][j] = MFMA(aph[p], blf[j], acc[p][j]);
                acc[p][j] = MFMA(apl[p], bhf[j], acc[p][j]);
            }
        SETPRIO(0);

        if (pf) asm volatile("s_waitcnt vmcnt(6)" ::: "memory");
        else    asm volatile("s_waitcnt vmcnt(0)" ::: "memory");
        BAR();
    }

    // ---- epilogue: per-wave LDS repack -> coalesced u16x8 split stores ----
    int proj = n0 >> 10;                    // 0=Q, 1=K
    const float* bias = proj ? bk : bq;
    u16* ohp = proj ? kh : qh;
    u16* olp = proj ? kl : ql;
    int wm = (wave >> 1) * 64, wn = (wave & 1) * 64;
    int q4 = lane >> 4, l16 = lane & 15;
    int cb = (n0 & 1023) + wn;
    float bj[4];
#pragma unroll
    for (int j = 0; j < 4; ++j) bj[j] = bias[cb + j * 16 + l16];
    float* repw = (float*)smem + wave * 2176;   // 32 rows x stride 68
    int r8 = lane >> 3, c8 = lane & 7;
#pragma unroll
    for (int gph = 0; gph < 2; ++gph) {
#pragma unroll
        for (int ii = 0; ii < 2; ++ii)
#pragma unroll
            for (int j = 0; j < 4; ++j)
#pragma unroll
                for (int r = 0; r < 4; ++r)
                    repw[(ii * 16 + q4 * 4 + r) * 68 + j * 16 + l16] =
                        acc[gph * 2 + ii][j][r] + bj[j];
#pragma unroll
        for (int rg = 0; rg < 4; ++rg) {
            int lr = rg * 8 + r8;
            float4 f0 = *(float4*)(repw + lr * 68 + c8 * 8);
            float4 f1 = *(float4*)(repw + lr * 68 + c8 * 8 + 4);
            float fa[8] = {f0.x, f0.y, f0.z, f0.w, f1.x, f1.y, f1.z, f1.w};
            size_t off = (size_t)(m0 + wm + gph * 32 + lr) * EDIM + cb + c8 * 8;
            u16x8 hv, lv;
#pragma unroll
            for (int e = 0; e < 8; ++e) {
                float v = fa[e];
                if (proj == 0) v *= 0.125f;
                u16 hh, ll;
                split2(v, hh, ll);
                hv[e] = hh; lv[e] = ll;
            }
            *(u16x8*)(ohp + off) = hv;
            *(u16x8*)(olp + off) = lv;
        }
    }
}

// ---------------------------------------------------------------------------
// V projection GEMM (1-pass hi*hi). BM=256, BN=128, BK=32, 512 thr
// (8 waves of 64x64), 3 LDS buffers + counted vmcnt(3), ONE barrier/K-step.
// grid = 256.
// ---------------------------------------------------------------------------
__global__ __launch_bounds__(512, 2) void gemm_v_kernel(
    const u16* __restrict__ Xh, const u16* __restrict__ Wv,
    const float* __restrict__ bv, u16* __restrict__ vh)
{
    __shared__ __align__(16) unsigned char smem[73728];   // 3 x 24 KB buffers
    u16* lds = (u16*)smem;

    int t = threadIdx.x;
    int lane = t & 63, wave = t >> 6;
    int bid = blockIdx.x;
    int wg = (bid & 7) * 32 + (bid >> 3);
    int bx = wg & 7, by = wg >> 3;
    int m0 = by * 256, nc0 = bx * 128;          // nc0: col within V's 1024

    int lrow = lane & 15, lq = lane >> 4;
    size_t aoff = (size_t)(m0 + wave * 32 + lrow) * EDIM + lq * 8;
    size_t boff = (size_t)(nc0 + wave * 16 + lrow) * EDIM + lq * 8;
    int slabA = wave * 2;
    int sA0 = (wave >> 1) * 4;                  // 4 m-frags
    int sB0 = (wave & 1) * 4;                   // 4 n-frags
    f32x4 acc[4][4] = {};

    // prologue: stage tiles 0 and 1
#pragma unroll
    for (int tt = 0; tt < 2; ++tt) {
        u16* sbuf = lds + tt * 12288;
        int kk = tt * 32;
        GLL(Xh + aoff + kk,             sbuf + (slabA + 0) * 512);
        GLL(Xh + aoff + kk + 16 * EDIM, sbuf + (slabA + 1) * 512);
        GLL(Wv + boff + kk,             sbuf + 8192 + wave * 512);
    }
    asm volatile("s_waitcnt vmcnt(3)" ::: "memory");
    BAR();

    for (int t32 = 0; t32 < 32; ++t32) {
        u16* rb = lds + (t32 % 3) * 12288;
        u16* sbuf = lds + ((t32 + 2) % 3) * 12288;
        bool pf = (t32 + 2) < 32;
        int kn = (t32 + 2) * 32;

        if (pf) {
            GLL(Xh + aoff + kn,             sbuf + (slabA + 0) * 512);
            GLL(Xh + aoff + kn + 16 * EDIM, sbuf + (slabA + 1) * 512);
            GLL(Wv + boff + kn, sbuf + 8192 + wave * 512);
        }

        bf16x8 bhf[4], af[4];
#pragma unroll
        for (int j = 0; j < 4; ++j)
            bhf[j] = *(const bf16x8*)(rb + 8192 + (sB0 + j) * 512 + lane * 8);
#pragma unroll
        for (int i = 0; i < 4; ++i)
            af[i] = *(const bf16x8*)(rb + (sA0 + i) * 512 + lane * 8);

        SETPRIO(1);
#pragma unroll
        for (int i = 0; i < 4; ++i)
#pragma unroll
            for (int j = 0; j < 4; ++j)
                acc[i][j] = MFMA(af[i], bhf[j], acc[i][j]);
        SETPRIO(0);

        if (pf) asm volatile("s_waitcnt vmcnt(3)" ::: "memory");
        else    asm volatile("s_waitcnt vmcnt(0)" ::: "memory");
        BAR();
    }

    // ---- epilogue ----
    int wm = (wave >> 1) * 64, wn = (wave & 1) * 64;
    int q4 = lane >> 4, l16 = lane & 15;
    int cb = nc0 + wn;
    float bj[4];
#pragma unroll
    for (int j = 0; j < 4; ++j) bj[j] = bv[cb + j * 16 + l16];
    float* repw = (float*)smem + wave * 2176;
    int r8 = lane >> 3, c8 = lane & 7;
#pragma unroll
    for (int gph = 0; gph < 2; ++gph) {
#pragma unroll
        for (int ii = 0; ii < 2; ++ii)
#pragma unroll
            for (int j = 0; j < 4; ++j)
#pragma unroll
                for (int r = 0; r < 4; ++r)
                    repw[(ii * 16 + q4 * 4 + r) * 68 + j * 16 + l16] =
                        acc[gph * 2 + ii][j][r] + bj[j];
#pragma unroll
        for (int rg = 0; rg < 4; ++rg) {
            int lr = rg * 8 + r8;
            float4 f0 = *(float4*)(repw + lr * 68 + c8 * 8);
            float4 f1 = *(float4*)(repw + lr * 68 + c8 * 8 + 4);
            float fa[8] = {f0.x, f0.y, f0.z, f0.w, f1.x, f1.y, f1.z, f1.w};
            size_t off = (size_t)(m0 + wm + gph * 32 + lr) * EDIM + cb + c8 * 8;
            u16x8 hv;
#pragma unroll
            for (int e = 0; e < 8; ++e) hv[e] = bf16rne(fa[e]);
            *(u16x8*)(vh + off) = hv;
        }
    }
}

// ---------------------------------------------------------------------------
// O projection GEMM (3-pass split), fp32 out. BM=256, BN=128, BK=32, 512 thr
// (8 waves of 64x64), 3 LDS buffers + counted vmcnt(6), ONE barrier/K-step.
// grid = 256 (32x8 tiles).
// ---------------------------------------------------------------------------
__global__ __launch_bounds__(512, 2) void gemm_o_kernel(
    const u16* __restrict__ Xh, const u16* __restrict__ Xl,
    const u16* __restrict__ Wh, const u16* __restrict__ Wl,
    const float* __restrict__ bias, float* __restrict__ Y)
{
    __shared__ __align__(16) unsigned char smem[147456];  // 3 x 48 KB buffers
    u16* lds = (u16*)smem;
    const int PA_h = 0, PA_l = 8192, PB_h = 16384, PB_l = 20480;  // u16 units

    int t = threadIdx.x;
    int lane = t & 63, wave = t >> 6;
    int bid = blockIdx.x;
    int wg = (bid & 7) * 32 + (bid >> 3);   // bijective over 256 (256%8==0)
    int bx = wg & 7, by = wg >> 3;          // 8 N-tiles x 32 M-tiles
    int m0 = by * 256, n0 = bx * 128;

    int lrow = lane & 15, lq = lane >> 4;
    size_t aoff = (size_t)(m0 + wave * 32 + lrow) * EDIM + lq * 8;
    size_t boff = (size_t)(n0 + wave * 16 + lrow) * EDIM + lq * 8;
    int slabA = wave * 2;
    int sA0 = (wave >> 1) * 4;
    int sB0 = (wave & 1) * 4;
    f32x4 acc[4][4] = {};

    // prologue: stage tiles 0 and 1
#pragma unroll
    for (int tt = 0; tt < 2; ++tt) {
        u16* sbuf = lds + tt * 24576;
        int kk = tt * 32;
        GLL(Xh + aoff + kk,             sbuf + PA_h + (slabA + 0) * 512);
        GLL(Xh + aoff + kk + 16 * EDIM, sbuf + PA_h + (slabA + 1) * 512);
        GLL(Xl + aoff + kk,             sbuf + PA_l + (slabA + 0) * 512);
        GLL(Xl + aoff + kk + 16 * EDIM, sbuf + PA_l + (slabA + 1) * 512);
        GLL(Wh + boff + kk, sbuf + PB_h + wave * 512);
        GLL(Wl + boff + kk, sbuf + PB_l + wave * 512);
    }
    asm volatile("s_waitcnt vmcnt(6)" ::: "memory");
    BAR();

    for (int t32 = 0; t32 < 32; ++t32) {
        u16* rb = lds + (t32 % 3) * 24576;
        u16* sbuf = lds + ((t32 + 2) % 3) * 24576;
        bool pf = (t32 + 2) < 32;
        int kn = (t32 + 2) * 32;

        if (pf) {
            GLL(Xh + aoff + kn,             sbuf + PA_h + (slabA + 0) * 512);
            GLL(Xh + aoff + kn + 16 * EDIM, sbuf + PA_h + (slabA + 1) * 512);
            GLL(Xl + aoff + kn,             sbuf + PA_l + (slabA + 0) * 512);
            GLL(Xl + aoff + kn + 16 * EDIM, sbuf + PA_l + (slabA + 1) * 512);
            GLL(Wh + boff + kn, sbuf + PB_h + wave * 512);
            GLL(Wl + boff + kn, sbuf + PB_l + wave * 512);
        }

        bf16x8 bhf[4], blf[4], aph[4], apl[4];
#pragma unroll
        for (int j = 0; j < 4; ++j) {
            bhf[j] = *(const bf16x8*)(rb + PB_h + (sB0 + j) * 512 + lane * 8);
            blf[j] = *(const bf16x8*)(rb + PB_l + (sB0 + j) * 512 + lane * 8);
        }
#pragma unroll
        for (int p = 0; p < 4; ++p) {
            aph[p] = *(const bf16x8*)(rb + PA_h + (sA0 + p) * 512 + lane * 8);
            apl[p] = *(const bf16x8*)(rb + PA_l + (sA0 + p) * 512 + lane * 8);
        }

        SETPRIO(1);
#pragma unroll
        for (int p = 0; p < 4; ++p)
#pragma unroll
            for (int j = 0; j < 4; ++j) {
                acc[p][j] = MFMA(aph[p], bhf[j], acc[p][j]);
                acc[p][j] = MFMA(aph[p], blf[j], acc[p][j]);
                acc[p][j] = MFMA(apl[p], bhf[j], acc[p][j]);
            }
        SETPRIO(0);

        if (pf) asm volatile("s_waitcnt vmcnt(6)" ::: "memory");
        else    asm volatile("s_waitcnt vmcnt(0)" ::: "memory");
        BAR();
    }

    int wm = (wave >> 1) * 64, wn = (wave & 1) * 64;
    int col_in = lane & 15, rquad = lane >> 4;
#pragma unroll
    for (int j = 0; j < 4; ++j) {
        int col = n0 + wn + j * 16 + col_in;
        float bvv = bias[col];
#pragma unroll
        for (int i = 0; i < 4; ++i) {
            int mbase = m0 + wm + i * 16 + rquad * 4;
#pragma unroll
            for (int r = 0; r < 4; ++r)
                Y[(size_t)(mbase + r) * EDIM + col] = acc[i][j][r] + bvv;
        }
    }
}

// ---------------------------------------------------------------------------
// MFMA flash attention v2 (proven structure from the 510 us run) + T5 setprio.
// K double-buffered via GLL (issued BEFORE compute, drained AFTER compute);
// V prefetched to regs alongside, scattered to LDS post-compute.
// T13 defer-max. ACC: accumulate into out (else store). OSPLIT: fuse hi/lo
// bf16 split of (out + contribution) into the epilogue (last scale).
// ---------------------------------------------------------------------------
template <int C, bool ACC, bool OSPLIT>
__global__ __launch_bounds__(256, 3) void attn_mfma_kernel(
    const u16* __restrict__ Qh, const u16* __restrict__ Ql,
    const u16* __restrict__ Kh, const u16* __restrict__ Kl,
    const u16* __restrict__ Vh, const int* __restrict__ sidx,
    float* __restrict__ out, u16* __restrict__ osh, u16* __restrict__ osl)
{
    __shared__ u16 KfH[2][4096], KfL[2][4096];   // dbuf K: [s(4)][kk(2)][lane][8]
    __shared__ u16 VL[64 * 72];                  // [dim(64)][key(64)] stride 72
    __shared__ u16 PbH[4 * 16 * 56];             // per-wave P, row stride 56

    int t = threadIdx.x;
    int lane = t & 63, wave = t >> 6;
    int quad = lane >> 4, l16 = lane & 15;
    int bh = blockIdx.y, b = bh >> 4, h = bh & 15;
    int p0 = blockIdx.x * 128;
    const int* sxb = sidx + b * NTOK;

    int ptile[2], ws_[2], we_[2];
    bf16x8 qhf[2][2], qlf[2][2];
#pragma unroll
    for (int tq = 0; tq < 2; ++tq) {
        ptile[tq] = p0 + wave * 32 + tq * 16;
        int c = ptile[tq] / C;
        ws_[tq] = (c > 0) ? (c - 1) * C : 0;
        we_[tq] = (c + 1) * C;
        int qrow = sxb[ptile[tq] + l16];
        size_t rb = (size_t)(b * NTOK + qrow) * EDIM + h * HDIM + quad * 8;
#pragma unroll
        for (int kk = 0; kk < 2; ++kk) {
            qhf[tq][kk] = *(const bf16x8*)(Qh + rb + kk * 32);
            qlf[tq][kk] = *(const bf16x8*)(Ql + rb + kk * 32);
        }
    }

    f32x4 oacc[2][4] = {};
    float lpart[2][4] = {};
    float mrun[2] = {-1e30f, -1e30f};

    int c0 = p0 / C, c1 = (p0 + 127) / C;
    int kmin = (c0 > 0) ? (c0 - 1) * C : 0;
    int kmax = (c1 + 1) * C;
    int nsteps = (kmax - kmin + 63) >> 6;

    // ---- prologue: stage step 0 ----
    {
        int tok = sxb[min(kmin + wave * 16 + l16, NTOK - 1)];
        size_t rb = (size_t)(b * NTOK + tok) * EDIM + h * HDIM + quad * 8;
        GLL(Kh + rb,      &KfH[0][(wave * 2 + 0) * 512]);
        GLL(Kh + rb + 32, &KfH[0][(wave * 2 + 1) * 512]);
        GLL(Kl + rb,      &KfL[0][(wave * 2 + 0) * 512]);
        GLL(Kl + rb + 32, &KfL[0][(wave * 2 + 1) * 512]);
        bf16x8 vreg[2];
#pragma unroll
        for (int it = 0; it < 2; ++it) {
            int c = it * 256 + t;
            int key = c & 63, dg = c >> 6;
            int tok2 = sxb[min(kmin + key, NTOK - 1)];
            vreg[it] = *(const bf16x8*)(Vh + (size_t)(b * NTOK + tok2) * EDIM + h * HDIM + dg * 8);
        }
#pragma unroll
        for (int it = 0; it < 2; ++it) {
            int c = it * 256 + t;
            int key = c & 63, dg = c >> 6;
#pragma unroll
            for (int e = 0; e < 8; ++e)
                VL[(dg * 8 + e) * 72 + key] = (u16)vreg[it][e];
        }
        asm volatile("s_waitcnt vmcnt(0)" ::: "memory");
        __syncthreads();
    }

    int pb = 0;
    for (int s = 0; s < nsteps; ++s) {
        int ks = kmin + s * 64;
        int nk = min(64, kmax - ks);
        bool pf = (s + 1) < nsteps;
        bf16x8 vreg[2];
        if (pf) {
            int ks2 = ks + 64;
            int tok = sxb[min(ks2 + wave * 16 + l16, NTOK - 1)];
            size_t rb = (size_t)(b * NTOK + tok) * EDIM + h * HDIM + quad * 8;
            GLL(Kh + rb,      &KfH[pb ^ 1][(wave * 2 + 0) * 512]);
            GLL(Kh + rb + 32, &KfH[pb ^ 1][(wave * 2 + 1) * 512]);
            GLL(Kl + rb,      &KfL[pb ^ 1][(wave * 2 + 0) * 512]);
            GLL(Kl + rb + 32, &KfL[pb ^ 1][(wave * 2 + 1) * 512]);
#pragma unroll
            for (int it = 0; it < 2; ++it) {
                int c = it * 256 + t;
                int key = c & 63, dg = c >> 6;
                int tok2 = sxb[min(ks2 + key, NTOK - 1)];
                vreg[it] = *(const bf16x8*)(Vh + (size_t)(b * NTOK + tok2) * EDIM + h * HDIM + dg * 8);
            }
        }

        // ---- compute step s from KfH[pb]/KfL[pb] + VL ----
        int jlo0 = max(ks, ws_[0]) - ks, jhi0 = min(ks + nk, we_[0]) - ks;
        int jlo1 = max(ks, ws_[1]) - ks, jhi1 = min(ks + nk, we_[1]) - ks;
        bool e0 = jlo0 < jhi0, e1 = jlo1 < jhi1;
        if (e0 || e1) {
            int glo = e0 ? (e1 ? min(jlo0, jlo1) : jlo0) : jlo1;
            int ghi = e0 ? (e1 ? max(jhi0, jhi1) : jhi0) : jhi1;
            const u16* kfh = &KfH[pb][0];
            const u16* kfl = &KfL[pb][0];

            for (int g0 = glo & ~31; g0 < ghi; g0 += 32) {
                int s0i = g0 >> 4;
                int s1i = min(s0i + 1, 3);
                bf16x8 kh0[2], kl0[2], kh1[2], kl1[2];
#pragma unroll
                for (int kk = 0; kk < 2; ++kk) {
                    kh0[kk] = *(const bf16x8*)(kfh + ((s0i * 2 + kk) * 64 + lane) * 8);
                    kl0[kk] = *(const bf16x8*)(kfl + ((s0i * 2 + kk) * 64 + lane) * 8);
                    kh1[kk] = *(const bf16x8*)(kfh + ((s1i * 2 + kk) * 64 + lane) * 8);
                    kl1[kk] = *(const bf16x8*)(kfl + ((s1i * 2 + kk) * 64 + lane) * 8);
                }
#pragma unroll
                for (int tq = 0; tq < 2; ++tq) {
                    int jl = tq ? jlo1 : jlo0, jh = tq ? jhi1 : jhi0;
                    bool v0 = (g0 >= jl) && (g0 < jh);
                    bool v1 = (g0 + 16 >= jl) && (g0 + 16 < jh);
                    if (!v0 && !v1) continue;
                    f32x4 sa = {0.f, 0.f, 0.f, 0.f}, sb2 = {0.f, 0.f, 0.f, 0.f};
                    SETPRIO(1);
                    if (v0) {
                        sa = MFMA(qhf[tq][0], kh0[0], sa);
                        sa = MFMA(qhf[tq][0], kl0[0], sa);
                        sa = MFMA(qlf[tq][0], kh0[0], sa);
                        sa = MFMA(qhf[tq][1], kh0[1], sa);
                        sa = MFMA(qhf[tq][1], kl0[1], sa);
                        sa = MFMA(qlf[tq][1], kh0[1], sa);
                    }
                    if (v1) {
                        sb2 = MFMA(qhf[tq][0], kh1[0], sb2);
                        sb2 = MFMA(qhf[tq][0], kl1[0], sb2);
                        sb2 = MFMA(qlf[tq][0], kh1[0], sb2);
                        sb2 = MFMA(qhf[tq][1], kh1[1], sb2);
                        sb2 = MFMA(qhf[tq][1], kl1[1], sb2);
                        sb2 = MFMA(qlf[tq][1], kh1[1], sb2);
                    }
                    SETPRIO(0);
                    float smax = -1e30f;
                    if (v0) smax = fmaxf(smax, fmaxf(fmaxf(sa[0], sa[1]), fmaxf(sa[2], sa[3])));
                    if (v1) smax = fmaxf(smax, fmaxf(fmaxf(sb2[0], sb2[1]), fmaxf(sb2[2], sb2[3])));
                    smax = fmaxf(smax, __shfl_xor(smax, 1));
                    smax = fmaxf(smax, __shfl_xor(smax, 2));
                    smax = fmaxf(smax, __shfl_xor(smax, 4));
                    smax = fmaxf(smax, __shfl_xor(smax, 8));
                    float mold = mrun[tq];
                    float mnew = mold;
                    if (smax > mold + 8.0f) {      // T13 defer-max (THR=8)
                        mnew = smax;
                        mrun[tq] = mnew;
                        float alpha = __expf(mold - mnew);
#pragma unroll
                        for (int r = 0; r < 4; ++r) lpart[tq][r] *= alpha;
#pragma unroll
                        for (int dt = 0; dt < 4; ++dt) {
                            oacc[tq][dt][0] *= alpha; oacc[tq][dt][1] *= alpha;
                            oacc[tq][dt][2] *= alpha; oacc[tq][dt][3] *= alpha;
                        }
                    }
                    u16* pbh = PbH + wave * 896;
#pragma unroll
                    for (int r = 0; r < 4; ++r) {
                        float pa = v0 ? __expf(sa[r] - mnew) : 0.f;
                        float pbv = v1 ? __expf(sb2[r] - mnew) : 0.f;
                        lpart[tq][r] += pa + pbv;
                        pbh[(quad * 4 + r) * 56 + l16] = bf16rne(pa);
                        pbh[(quad * 4 + r) * 56 + 16 + l16] = bf16rne(pbv);
                    }
                    bf16x8 ph = *(const bf16x8*)(pbh + l16 * 56 + quad * 8);
                    int kh2 = g0 >> 5;
                    SETPRIO(1);
#pragma unroll
                    for (int dt = 0; dt < 4; ++dt) {
                        bf16x8 vv = *(const bf16x8*)(VL + (dt * 16 + l16) * 72 + kh2 * 32 + quad * 8);
                        oacc[tq][dt] = MFMA(ph, vv, oacc[tq][dt]);
                    }
                    SETPRIO(0);
                }
            }
        }

        asm volatile("s_waitcnt vmcnt(0)" ::: "memory");
        __syncthreads();                 // all waves done reading VL / K done
        if (pf) {
#pragma unroll
            for (int it = 0; it < 2; ++it) {
                int c = it * 256 + t;
                int key = c & 63, dg = c >> 6;
#pragma unroll
                for (int e = 0; e < 8; ++e)
                    VL[(dg * 8 + e) * 72 + key] = (u16)vreg[it][e];
            }
        }
        __syncthreads();                 // VL(t+1) ready
        pb ^= 1;
    }

#pragma unroll
    for (int tq = 0; tq < 2; ++tq) {
        float inv[4];
#pragma unroll
        for (int r = 0; r < 4; ++r) {
            float v = lpart[tq][r];
            v += __shfl_xor(v, 1);
            v += __shfl_xor(v, 2);
            v += __shfl_xor(v, 4);
            v += __shfl_xor(v, 8);
            inv[r] = 1.0f / (3.0f * v);
        }
#pragma unroll
        for (int r = 0; r < 4; ++r) {
            int tok = sxb[ptile[tq] + quad * 4 + r];
            size_t base = (size_t)(b * NTOK + tok) * EDIM + h * HDIM + l16;
            if (OSPLIT) {
#pragma unroll
                for (int dt = 0; dt < 4; ++dt) {
                    float v = out[base + dt * 16] + oacc[tq][dt][r] * inv[r];
                    u16 hh, ll;
                    split2(v, hh, ll);
                    osh[base + dt * 16] = hh;
                    osl[base + dt * 16] = ll;
                }
            } else if (ACC) {
#pragma unroll
                for (int dt = 0; dt < 4; ++dt)
                    out[base + dt * 16] += oacc[tq][dt][r] * inv[r];
            } else {
#pragma unroll
                for (int dt = 0; dt < 4; ++dt)
                    out[base + dt * 16] = oacc[tq][dt][r] * inv[r];
            }
        }
    }
}

// ---------------------------------------------------------------------------
extern "C" void kernel_launch(void* const* d_in, const int* in_sizes, int n_in,
                              void* d_out, int out_size, void* d_ws, size_t ws_size,
                              hipStream_t stream)
{
    const float* x   = (const float*)d_in[0];
    const int*   wbc = (const int*)d_in[1];
    const int*   wbm = (const int*)d_in[2];
    const int*   wbf = (const int*)d_in[3];
    const float* Wq = (const float*)d_in[4],  *bq = (const float*)d_in[5];
    const float* Aq = (const float*)d_in[6],  *Bq = (const float*)d_in[7];
    const float* Wk = (const float*)d_in[8],  *bk = (const float*)d_in[9];
    const float* Ak = (const float*)d_in[10], *Bk = (const float*)d_in[11];
    const float* Wv = (const float*)d_in[12], *bv = (const float*)d_in[13];
    const float* Av = (const float*)d_in[14], *Bv = (const float*)d_in[15];
    const float* Wo = (const float*)d_in[16], *bo = (const float*)d_in[17];
    const float* Ao = (const float*)d_in[18], *Bo = (const float*)d_in[19];

    const size_t EE  = (size_t)EDIM * EDIM;        // 1,048,576
    const size_t BNE = (size_t)MROWS * EDIM;       // 8,388,608

    char* wsb = (char*)d_ws;
    float* ab = (float*)wsb;                        wsb += BNE * 4;   // attn accum
    u16* xh = (u16*)wsb;                            wsb += BNE * 2;   // also abh
    u16* xl = (u16*)wsb;                            wsb += BNE * 2;   // also abl
    u16* qh = (u16*)wsb;                            wsb += BNE * 2;
    u16* ql = (u16*)wsb;                            wsb += BNE * 2;
    u16* kh = (u16*)wsb;                            wsb += BNE * 2;
    u16* kl = (u16*)wsb;                            wsb += BNE * 2;
    u16* vh = (u16*)wsb;                            wsb += BNE * 2;
    u16* wh_all = (u16*)wsb;                        wsb += 3 * EE * 2; // [q|k|v] hi
    u16* wl_all = (u16*)wsb;                        wsb += 3 * EE * 2; // [q|k|v] lo
    u16* woh = (u16*)wsb;                           wsb += EE * 2;
    u16* wol = (u16*)wsb;                           wsb += EE * 2;
    int* sidx = (int*)wsb;                          wsb += 3 * BDIM * NTOK * 4;

    split_kernel<<<BNE / 1024, 256, 0, stream>>>(x, xh, xl);

    build_weff4_kernel<<<dim3(4096, 4), 256, 0, stream>>>(
        Wq, Aq, Bq, Wk, Ak, Bk, Wv, Av, Bv, Wo, Ao, Bo,
        wh_all + 0 * EE, wl_all + 0 * EE,
        wh_all + 1 * EE, wl_all + 1 * EE,
        wh_all + 2 * EE, wl_all + 2 * EE,
        woh, wol);

    sort3_kernel<<<dim3(BDIM, 3), 256, 0, stream>>>(wbc, wbm, wbf, sidx);

    // QK projection (N = 2048, split-bf16 3-pass), 512 blocks x 512 thr
    gemm_qk_kernel<<<512, 512, 0, stream>>>(xh, xl, wh_all, wl_all,
                                            bq, bk, qh, ql, kh, kl);
    // V projection (N = 1024, 1-pass), 256 blocks x 512 thr
    gemm_v_kernel<<<256, 512, 0, stream>>>(xh, wh_all + 2 * EE, bv, vh);

    dim3 ga(NTOK / 128, BDIM * HEADS);  // (32, 32)
    // scale 0 stores (no memset needed); scale 1 accumulates;
    // scale 2 accumulates + fused hi/lo split of the sum into xh/xl.
    attn_mfma_kernel<256, false, false><<<ga, 256, 0, stream>>>(
        qh, ql, kh, kl, vh, sidx + 0 * BDIM * NTOK, ab, xh, xl);
    attn_mfma_kernel<64, true, false><<<ga, 256, 0, stream>>>(
        qh, ql, kh, kl, vh, sidx + 1 * BDIM * NTOK, ab, xh, xl);
    attn_mfma_kernel<16, true, true><<<ga, 256, 0, stream>>>(
        qh, ql, kh, kl, vh, sidx + 2 * BDIM * NTOK, ab, xh, xl);

    // O projection (256 blocks = 32x8 tiles) consumes the fused split directly
    gemm_o_kernel<<<256, 512, 0, stream>>>(xh, xl, woh, wol, bo, (float*)d_out);
}

// Round 7
// 481.515 us; speedup vs baseline: 1.0711x; 1.0711x over previous
//
#include <hip/hip_runtime.h>
#include <cstdint>
#include <cstddef>

// Problem constants
#define BDIM 2
#define NTOK 4096
#define EDIM 1024
#define HEADS 16
#define HDIM 64
#define MROWS (BDIM * NTOK)   // 8192

typedef unsigned short u16;
typedef __attribute__((ext_vector_type(8))) short bf16x8;   // 8 bf16 = 4 VGPR
typedef __attribute__((ext_vector_type(8))) unsigned short u16x8;
typedef __attribute__((ext_vector_type(4))) float f32x4;

#define MFMA(a, b, c) __builtin_amdgcn_mfma_f32_16x16x32_bf16(a, b, c, 0, 0, 0)
#define BAR() asm volatile("s_barrier" ::: "memory")
#define SETPRIO(p) __builtin_amdgcn_s_setprio(p)

// round-to-nearest-even split of fp32 into hi/lo bf16
__device__ inline void split2(float x, u16& h, u16& l) {
    union { float f; unsigned u; } a;
    a.f = x;
    unsigned uh = a.u + 0x7fff + ((a.u >> 16) & 1);
    h = (u16)(uh >> 16);
    union { unsigned u; float f; } hf; hf.u = (unsigned)h << 16;
    a.f = x - hf.f;
    unsigned ul = a.u + 0x7fff + ((a.u >> 16) & 1);
    l = (u16)(ul >> 16);
}

__device__ inline u16 bf16rne(float x) {
    union { float f; unsigned u; } a; a.f = x;
    unsigned r = a.u + 0x7fff + ((a.u >> 16) & 1);
    return (u16)(r >> 16);
}

// global -> LDS direct 16B staging (lane i lands at lds_base + i*16)
#define GLL(gp, lp) __builtin_amdgcn_global_load_lds( \
    (const __attribute__((address_space(1))) unsigned*)(gp), \
    (__attribute__((address_space(3))) unsigned*)(lp), 16, 0, 0)

// ---------------------------------------------------------------------------
// W_eff = W + 2*B@A for all 4 projections in one launch. grid=(4096,4)
// ---------------------------------------------------------------------------
__global__ __launch_bounds__(256) void build_weff4_kernel(
    const float* __restrict__ W0, const float* __restrict__ A0, const float* __restrict__ B0,
    const float* __restrict__ W1, const float* __restrict__ A1, const float* __restrict__ B1,
    const float* __restrict__ W2, const float* __restrict__ A2, const float* __restrict__ B2,
    const float* __restrict__ W3, const float* __restrict__ A3, const float* __restrict__ B3,
    u16* __restrict__ dh0, u16* __restrict__ dl0,
    u16* __restrict__ dh1, u16* __restrict__ dl1,
    u16* __restrict__ dh2, u16* __restrict__ dl2,
    u16* __restrict__ dh3, u16* __restrict__ dl3)
{
    int s = blockIdx.y;
    const float* W = (s == 0) ? W0 : (s == 1) ? W1 : (s == 2) ? W2 : W3;
    const float* A = (s == 0) ? A0 : (s == 1) ? A1 : (s == 2) ? A2 : A3;
    const float* Bm = (s == 0) ? B0 : (s == 1) ? B1 : (s == 2) ? B2 : B3;
    u16* dh = (s == 0) ? dh0 : (s == 1) ? dh1 : (s == 2) ? dh2 : dh3;
    u16* dl = (s == 0) ? dl0 : (s == 1) ? dl1 : (s == 2) ? dl2 : dl3;

    int idx = blockIdx.x * 256 + threadIdx.x;      // over E*E
    int o = idx >> 10, i = idx & 1023;
    float sum = 0.f;
#pragma unroll
    for (int r = 0; r < 8; ++r) sum += Bm[o * 8 + r] * A[r * 1024 + i];
    float w = W[idx] + 2.0f * sum;
    u16 h, l;
    split2(w, h, l);
    dh[idx] = h; dl[idx] = l;
}

// ---------------------------------------------------------------------------
// fp32 buffer -> hi/lo bf16 buffers, 4 elements / thread
// ---------------------------------------------------------------------------
__global__ __launch_bounds__(256) void split_kernel(
    const float* __restrict__ src, u16* __restrict__ dh, u16* __restrict__ dl)
{
    int idx = blockIdx.x * 256 + threadIdx.x;      // one float4
    float4 v = ((const float4*)src)[idx];
    ushort4 h, l;
    split2(v.x, h.x, l.x);
    split2(v.y, h.y, l.y);
    split2(v.z, h.z, l.z);
    split2(v.w, h.w, l.w);
    ((ushort4*)dh)[idx] = h;
    ((ushort4*)dl)[idx] = l;
}

// ---------------------------------------------------------------------------
// (A + B + C) -> hi/lo bf16 split, 4 elements / thread (merged-attn path)
// ---------------------------------------------------------------------------
__global__ __launch_bounds__(256) void sumsplit3_kernel(
    const float* __restrict__ A, const float* __restrict__ B,
    const float* __restrict__ Cc, u16* __restrict__ dh, u16* __restrict__ dl)
{
    int idx = blockIdx.x * 256 + threadIdx.x;      // one float4
    float4 a = ((const float4*)A)[idx];
    float4 b = ((const float4*)B)[idx];
    float4 c = ((const float4*)Cc)[idx];
    float v[4] = {(a.x + b.x) + c.x, (a.y + b.y) + c.y,
                  (a.z + b.z) + c.z, (a.w + b.w) + c.w};
    ushort4 h, l;
    split2(v[0], h.x, l.x);
    split2(v[1], h.y, l.y);
    split2(v[2], h.z, l.z);
    split2(v[3], h.w, l.w);
    ((ushort4*)dh)[idx] = h;
    ((ushort4*)dl)[idx] = l;
}

// ---------------------------------------------------------------------------
// Parallel stable counting sort, 3 scales x BDIM batches. grid=(BDIM,3).
// ---------------------------------------------------------------------------
__global__ __launch_bounds__(256) void sort3_kernel(
    const int* __restrict__ w0, const int* __restrict__ w1,
    const int* __restrict__ w2, int* __restrict__ sidx)
{
    __shared__ int sb[NTOK];          // 16 KB
    __shared__ int cnt[32][256];      // 32 KB
    __shared__ int gb[256];           // 1 KB
    const int* srcs[3] = {w0, w1, w2};
    int t = threadIdx.x;
    const int* w = srcs[blockIdx.y] + blockIdx.x * NTOK;
    int* outp = sidx + ((int)blockIdx.y * BDIM + (int)blockIdx.x) * NTOK;

    for (int i = t; i < NTOK; i += 256) sb[i] = w[i];
    for (int i = t; i < 32 * 256; i += 256) ((int*)cnt)[i] = 0;
    __syncthreads();

    int g = t >> 3;
#pragma unroll
    for (int e = 0; e < 16; ++e)
        atomicAdd(&cnt[g][sb[g * 128 + (t & 7) + 8 * e]], 1);
    __syncthreads();

    int run = 0;
#pragma unroll
    for (int gg = 0; gg < 32; ++gg) {
        int c = cnt[gg][t];
        cnt[gg][t] = run;
        run += c;
    }
    gb[t] = run;
    __syncthreads();
    if (t == 0) {
        int acc = 0;
        for (int v = 0; v < 256; ++v) { int c = gb[v]; gb[v] = acc; acc += c; }
    }
    __syncthreads();
    for (int i = t; i < 32 * 256; i += 256) {
        int v = i & 255, gg = i >> 8;
        cnt[gg][v] += gb[v];
    }
    __syncthreads();

    if (t < 32) {
        int base = t * 128;
        for (int e = 0; e < 128; ++e) {
            int v = sb[base + e];
            int p = cnt[t][v]++;
            outp[p] = base + e;
        }
    }
}

// ---------------------------------------------------------------------------
// QK split-bf16 MFMA GEMM (3-pass). BM=256, BN=128, BK=32, 512 thr
// (8 waves of 64x64), 3 LDS buffers + counted vmcnt(6), 4-phase interleave
// (r5-proven: 117 us / 37% MfmaUtil). grid = 512.
// ---------------------------------------------------------------------------
__global__ __launch_bounds__(512, 2) void gemm_qk_kernel(
    const u16* __restrict__ Xh, const u16* __restrict__ Xl,
    const u16* __restrict__ Wh, const u16* __restrict__ Wl,
    const float* __restrict__ bq, const float* __restrict__ bk,
    u16* __restrict__ qh, u16* __restrict__ ql,
    u16* __restrict__ kh, u16* __restrict__ kl)
{
    __shared__ __align__(16) unsigned char smem[147456];  // 3 x 48 KB buffers
    u16* lds = (u16*)smem;
    const int PA_h = 0, PA_l = 8192, PB_h = 16384, PB_l = 20480;  // u16 units

    int t = threadIdx.x;
    int lane = t & 63, wave = t >> 6;
    int bid = blockIdx.x;
    int wg = (bid & 7) * 64 + (bid >> 3);   // XCD-bijective swizzle (512%8==0)
    int bx = wg & 15, by = wg >> 4;
    int m0 = by * 256, n0 = bx * 128;       // n0 in [0,2048)

    int lrow = lane & 15, lq = lane >> 4;
    size_t aoff = (size_t)(m0 + wave * 32 + lrow) * EDIM + lq * 8;
    size_t boff = (size_t)(n0 + wave * 16 + lrow) * EDIM + lq * 8;
    int slabA = wave * 2;
    int sA0 = (wave >> 1) * 4;
    int sB0 = (wave & 1) * 4;
    f32x4 acc[4][4] = {};

    // prologue: stage tiles 0 and 1
#pragma unroll
    for (int tt = 0; tt < 2; ++tt) {
        u16* sbuf = lds + tt * 24576;
        int kk = tt * 32;
        GLL(Xh + aoff + kk,             sbuf + PA_h + (slabA + 0) * 512);
        GLL(Xh + aoff + kk + 16 * EDIM, sbuf + PA_h + (slabA + 1) * 512);
        GLL(Xl + aoff + kk,             sbuf + PA_l + (slabA + 0) * 512);
        GLL(Xl + aoff + kk + 16 * EDIM, sbuf + PA_l + (slabA + 1) * 512);
        GLL(Wh + boff + kk, sbuf + PB_h + wave * 512);
        GLL(Wl + boff + kk, sbuf + PB_l + wave * 512);
    }
    asm volatile("s_waitcnt vmcnt(6)" ::: "memory");
    BAR();

    for (int t32 = 0; t32 < 32; ++t32) {
        u16* rb = lds + (t32 % 3) * 24576;
        u16* sbuf = lds + ((t32 + 2) % 3) * 24576;
        bool pf = (t32 + 2) < 32;
        int kn = (t32 + 2) * 32;
        bf16x8 bhf[4], blf[4];
#pragma unroll
        for (int p = 0; p < 4; ++p) {
            if (p == 0) {
#pragma unroll
                for (int j = 0; j < 4; ++j) {
                    bhf[j] = *(const bf16x8*)(rb + PB_h + (sB0 + j) * 512 + lane * 8);
                    blf[j] = *(const bf16x8*)(rb + PB_l + (sB0 + j) * 512 + lane * 8);
                }
            }
            bf16x8 aph = *(const bf16x8*)(rb + PA_h + (sA0 + p) * 512 + lane * 8);
            bf16x8 apl = *(const bf16x8*)(rb + PA_l + (sA0 + p) * 512 + lane * 8);
            if (pf) {
                if (p == 0) {
                    GLL(Xh + aoff + kn,             sbuf + PA_h + (slabA + 0) * 512);
                    GLL(Xh + aoff + kn + 16 * EDIM, sbuf + PA_h + (slabA + 1) * 512);
                } else if (p == 1) {
                    GLL(Xl + aoff + kn,             sbuf + PA_l + (slabA + 0) * 512);
                    GLL(Xl + aoff + kn + 16 * EDIM, sbuf + PA_l + (slabA + 1) * 512);
                } else if (p == 2) {
                    GLL(Wh + boff + kn, sbuf + PB_h + wave * 512);
                    GLL(Wl + boff + kn, sbuf + PB_l + wave * 512);
                }
            }
            BAR();
            SETPRIO(1);
#pragma unroll
            for (int j = 0; j < 4; ++j) {
                acc[p][j] = MFMA(aph, bhf[j], acc[p][j]);
                acc[p][j] = MFMA(aph, blf[j], acc[p][j]);
                acc[p][j] = MFMA(apl, bhf[j], acc[p][j]);
            }
            SETPRIO(0);
            if (p == 3) {
                if (pf) asm volatile("s_waitcnt vmcnt(6)" ::: "memory");
                else    asm volatile("s_waitcnt vmcnt(0)" ::: "memory");
            }
            BAR();
        }
    }

    // ---- epilogue: per-wave LDS repack -> coalesced u16x8 split stores ----
    int proj = n0 >> 10;                    // 0=Q, 1=K
    const float* bias = proj ? bk : bq;
    u16* ohp = proj ? kh : qh;
    u16* olp = proj ? kl : ql;
    int wm = (wave >> 1) * 64, wn = (wave & 1) * 64;
    int q4 = lane >> 4, l16 = lane & 15;
    int cb = (n0 & 1023) + wn;
    float bj[4];
#pragma unroll
    for (int j = 0; j < 4; ++j) bj[j] = bias[cb + j * 16 + l16];
    float* repw = (float*)smem + wave * 2176;   // 32 rows x stride 68
    int r8 = lane >> 3, c8 = lane & 7;
#pragma unroll
    for (int gph = 0; gph < 2; ++gph) {
#pragma unroll
        for (int ii = 0; ii < 2; ++ii)
#pragma unroll
            for (int j = 0; j < 4; ++j)
#pragma unroll
                for (int r = 0; r < 4; ++r)
                    repw[(ii * 16 + q4 * 4 + r) * 68 + j * 16 + l16] =
                        acc[gph * 2 + ii][j][r] + bj[j];
#pragma unroll
        for (int rg = 0; rg < 4; ++rg) {
            int lr = rg * 8 + r8;
            float4 f0 = *(float4*)(repw + lr * 68 + c8 * 8);
            float4 f1 = *(float4*)(repw + lr * 68 + c8 * 8 + 4);
            float fa[8] = {f0.x, f0.y, f0.z, f0.w, f1.x, f1.y, f1.z, f1.w};
            size_t off = (size_t)(m0 + wm + gph * 32 + lr) * EDIM + cb + c8 * 8;
            u16x8 hv, lv;
#pragma unroll
            for (int e = 0; e < 8; ++e) {
                float v = fa[e];
                if (proj == 0) v *= 0.125f;
                u16 hh, ll;
                split2(v, hh, ll);
                hv[e] = hh; lv[e] = ll;
            }
            *(u16x8*)(ohp + off) = hv;
            *(u16x8*)(olp + off) = lv;
        }
    }
}

// ---------------------------------------------------------------------------
// V projection GEMM (1-pass hi*hi). BM=256, BN=128, BK=32, 512 thr
// (8 waves of 64x64), 3 LDS buffers + counted vmcnt(3), 2-phase (r5-proven).
// grid = 256.
// ---------------------------------------------------------------------------
__global__ __launch_bounds__(512, 2) void gemm_v_kernel(
    const u16* __restrict__ Xh, const u16* __restrict__ Wv,
    const float* __restrict__ bv, u16* __restrict__ vh)
{
    __shared__ __align__(16) unsigned char smem[73728];   // 3 x 24 KB buffers
    u16* lds = (u16*)smem;

    int t = threadIdx.x;
    int lane = t & 63, wave = t >> 6;
    int bid = blockIdx.x;
    int wg = (bid & 7) * 32 + (bid >> 3);
    int bx = wg & 7, by = wg >> 3;
    int m0 = by * 256, nc0 = bx * 128;          // nc0: col within V's 1024

    int lrow = lane & 15, lq = lane >> 4;
    size_t aoff = (size_t)(m0 + wave * 32 + lrow) * EDIM + lq * 8;
    size_t boff = (size_t)(nc0 + wave * 16 + lrow) * EDIM + lq * 8;
    int slabA = wave * 2;
    int sA0 = (wave >> 1) * 4;                  // 4 m-frags
    int sB0 = (wave & 1) * 4;                   // 4 n-frags
    f32x4 acc[4][4] = {};

    // prologue: stage tiles 0 and 1
#pragma unroll
    for (int tt = 0; tt < 2; ++tt) {
        u16* sbuf = lds + tt * 12288;
        int kk = tt * 32;
        GLL(Xh + aoff + kk,             sbuf + (slabA + 0) * 512);
        GLL(Xh + aoff + kk + 16 * EDIM, sbuf + (slabA + 1) * 512);
        GLL(Wv + boff + kk,             sbuf + 8192 + wave * 512);
    }
    asm volatile("s_waitcnt vmcnt(3)" ::: "memory");
    BAR();

    for (int t32 = 0; t32 < 32; ++t32) {
        u16* rb = lds + (t32 % 3) * 12288;
        u16* sbuf = lds + ((t32 + 2) % 3) * 12288;
        bool pf = (t32 + 2) < 32;
        int kn = (t32 + 2) * 32;

        bf16x8 bhf[4];
#pragma unroll
        for (int j = 0; j < 4; ++j)
            bhf[j] = *(const bf16x8*)(rb + 8192 + (sB0 + j) * 512 + lane * 8);
        bf16x8 a0 = *(const bf16x8*)(rb + (sA0 + 0) * 512 + lane * 8);
        bf16x8 a1 = *(const bf16x8*)(rb + (sA0 + 1) * 512 + lane * 8);
        if (pf) {
            GLL(Xh + aoff + kn,             sbuf + (slabA + 0) * 512);
            GLL(Xh + aoff + kn + 16 * EDIM, sbuf + (slabA + 1) * 512);
        }
        BAR();
        SETPRIO(1);
#pragma unroll
        for (int j = 0; j < 4; ++j) {
            acc[0][j] = MFMA(a0, bhf[j], acc[0][j]);
            acc[1][j] = MFMA(a1, bhf[j], acc[1][j]);
        }
        SETPRIO(0);
        BAR();

        bf16x8 a2 = *(const bf16x8*)(rb + (sA0 + 2) * 512 + lane * 8);
        bf16x8 a3 = *(const bf16x8*)(rb + (sA0 + 3) * 512 + lane * 8);
        if (pf) GLL(Wv + boff + kn, sbuf + 8192 + wave * 512);
        BAR();
        SETPRIO(1);
#pragma unroll
        for (int j = 0; j < 4; ++j) {
            acc[2][j] = MFMA(a2, bhf[j], acc[2][j]);
            acc[3][j] = MFMA(a3, bhf[j], acc[3][j]);
        }
        SETPRIO(0);
        if (pf) asm volatile("s_waitcnt vmcnt(3)" ::: "memory");
        else    asm volatile("s_waitcnt vmcnt(0)" ::: "memory");
        BAR();
    }

    // ---- epilogue ----
    int wm = (wave >> 1) * 64, wn = (wave & 1) * 64;
    int q4 = lane >> 4, l16 = lane & 15;
    int cb = nc0 + wn;
    float bj[4];
#pragma unroll
    for (int j = 0; j < 4; ++j) bj[j] = bv[cb + j * 16 + l16];
    float* repw = (float*)smem + wave * 2176;
    int r8 = lane >> 3, c8 = lane & 7;
#pragma unroll
    for (int gph = 0; gph < 2; ++gph) {
#pragma unroll
        for (int ii = 0; ii < 2; ++ii)
#pragma unroll
            for (int j = 0; j < 4; ++j)
#pragma unroll
                for (int r = 0; r < 4; ++r)
                    repw[(ii * 16 + q4 * 4 + r) * 68 + j * 16 + l16] =
                        acc[gph * 2 + ii][j][r] + bj[j];
#pragma unroll
        for (int rg = 0; rg < 4; ++rg) {
            int lr = rg * 8 + r8;
            float4 f0 = *(float4*)(repw + lr * 68 + c8 * 8);
            float4 f1 = *(float4*)(repw + lr * 68 + c8 * 8 + 4);
            float fa[8] = {f0.x, f0.y, f0.z, f0.w, f1.x, f1.y, f1.z, f1.w};
            size_t off = (size_t)(m0 + wm + gph * 32 + lr) * EDIM + cb + c8 * 8;
            u16x8 hv;
#pragma unroll
            for (int e = 0; e < 8; ++e) hv[e] = bf16rne(fa[e]);
            *(u16x8*)(vh + off) = hv;
        }
    }
}

// ---------------------------------------------------------------------------
// O projection GEMM (3-pass split), fp32 out. BM=256, BN=128, BK=32, 512 thr
// (8 waves of 64x64), 3 LDS buffers + counted vmcnt(6), 4-phase (r5-proven).
// grid = 256 (32x8 tiles).
// ---------------------------------------------------------------------------
__global__ __launch_bounds__(512, 2) void gemm_o_kernel(
    const u16* __restrict__ Xh, const u16* __restrict__ Xl,
    const u16* __restrict__ Wh, const u16* __restrict__ Wl,
    const float* __restrict__ bias, float* __restrict__ Y)
{
    __shared__ __align__(16) unsigned char smem[147456];  // 3 x 48 KB buffers
    u16* lds = (u16*)smem;
    const int PA_h = 0, PA_l = 8192, PB_h = 16384, PB_l = 20480;  // u16 units

    int t = threadIdx.x;
    int lane = t & 63, wave = t >> 6;
    int bid = blockIdx.x;
    int wg = (bid & 7) * 32 + (bid >> 3);   // bijective over 256 (256%8==0)
    int bx = wg & 7, by = wg >> 3;          // 8 N-tiles x 32 M-tiles
    int m0 = by * 256, n0 = bx * 128;

    int lrow = lane & 15, lq = lane >> 4;
    size_t aoff = (size_t)(m0 + wave * 32 + lrow) * EDIM + lq * 8;
    size_t boff = (size_t)(n0 + wave * 16 + lrow) * EDIM + lq * 8;
    int slabA = wave * 2;
    int sA0 = (wave >> 1) * 4;
    int sB0 = (wave & 1) * 4;
    f32x4 acc[4][4] = {};

    // prologue: stage tiles 0 and 1
#pragma unroll
    for (int tt = 0; tt < 2; ++tt) {
        u16* sbuf = lds + tt * 24576;
        int kk = tt * 32;
        GLL(Xh + aoff + kk,             sbuf + PA_h + (slabA + 0) * 512);
        GLL(Xh + aoff + kk + 16 * EDIM, sbuf + PA_h + (slabA + 1) * 512);
        GLL(Xl + aoff + kk,             sbuf + PA_l + (slabA + 0) * 512);
        GLL(Xl + aoff + kk + 16 * EDIM, sbuf + PA_l + (slabA + 1) * 512);
        GLL(Wh + boff + kk, sbuf + PB_h + wave * 512);
        GLL(Wl + boff + kk, sbuf + PB_l + wave * 512);
    }
    asm volatile("s_waitcnt vmcnt(6)" ::: "memory");
    BAR();

    for (int t32 = 0; t32 < 32; ++t32) {
        u16* rb = lds + (t32 % 3) * 24576;
        u16* sbuf = lds + ((t32 + 2) % 3) * 24576;
        bool pf = (t32 + 2) < 32;
        int kn = (t32 + 2) * 32;
        bf16x8 bhf[4], blf[4];
#pragma unroll
        for (int p = 0; p < 4; ++p) {
            if (p == 0) {
#pragma unroll
                for (int j = 0; j < 4; ++j) {
                    bhf[j] = *(const bf16x8*)(rb + PB_h + (sB0 + j) * 512 + lane * 8);
                    blf[j] = *(const bf16x8*)(rb + PB_l + (sB0 + j) * 512 + lane * 8);
                }
            }
            bf16x8 aph = *(const bf16x8*)(rb + PA_h + (sA0 + p) * 512 + lane * 8);
            bf16x8 apl = *(const bf16x8*)(rb + PA_l + (sA0 + p) * 512 + lane * 8);
            if (pf) {
                if (p == 0) {
                    GLL(Xh + aoff + kn,             sbuf + PA_h + (slabA + 0) * 512);
                    GLL(Xh + aoff + kn + 16 * EDIM, sbuf + PA_h + (slabA + 1) * 512);
                } else if (p == 1) {
                    GLL(Xl + aoff + kn,             sbuf + PA_l + (slabA + 0) * 512);
                    GLL(Xl + aoff + kn + 16 * EDIM, sbuf + PA_l + (slabA + 1) * 512);
                } else if (p == 2) {
                    GLL(Wh + boff + kn, sbuf + PB_h + wave * 512);
                    GLL(Wl + boff + kn, sbuf + PB_l + wave * 512);
                }
            }
            BAR();
            SETPRIO(1);
#pragma unroll
            for (int j = 0; j < 4; ++j) {
                acc[p][j] = MFMA(aph, bhf[j], acc[p][j]);
                acc[p][j] = MFMA(aph, blf[j], acc[p][j]);
                acc[p][j] = MFMA(apl, bhf[j], acc[p][j]);
            }
            SETPRIO(0);
            if (p == 3) {
                if (pf) asm volatile("s_waitcnt vmcnt(6)" ::: "memory");
                else    asm volatile("s_waitcnt vmcnt(0)" ::: "memory");
            }
            BAR();
        }
    }

    int wm = (wave >> 1) * 64, wn = (wave & 1) * 64;
    int col_in = lane & 15, rquad = lane >> 4;
#pragma unroll
    for (int j = 0; j < 4; ++j) {
        int col = n0 + wn + j * 16 + col_in;
        float bvv = bias[col];
#pragma unroll
        for (int i = 0; i < 4; ++i) {
            int mbase = m0 + wm + i * 16 + rquad * 4;
#pragma unroll
            for (int r = 0; r < 4; ++r)
                Y[(size_t)(mbase + r) * EDIM + col] = acc[i][j][r] + bvv;
        }
    }
}

// ---------------------------------------------------------------------------
// MFMA flash attention (r5-proven pipeline). Runtime scale s = blockIdx.z +
// zofs selects C = 256>>(2s) and the sidx slice; MODE: 0=store to per-scale
// buffer, 1=accumulate into out, 2=accumulate + fused hi/lo split epilogue.
// Merged path launches grid.z=3 with MODE=0 (scales run CONCURRENTLY, each
// to its own buffer -> no races, 3x the resident waves for latency hiding).
// ---------------------------------------------------------------------------
template <int MODE>
__global__ __launch_bounds__(256, 3) void attn_mfma_kernel(
    const u16* __restrict__ Qh, const u16* __restrict__ Ql,
    const u16* __restrict__ Kh, const u16* __restrict__ Kl,
    const u16* __restrict__ Vh, const int* __restrict__ sidx_base, int zofs,
    float* __restrict__ out0, float* __restrict__ out1, float* __restrict__ out2,
    u16* __restrict__ osh, u16* __restrict__ osl)
{
    __shared__ u16 KfH[2][4096], KfL[2][4096];   // dbuf K: [s(4)][kk(2)][lane][8]
    __shared__ u16 VL[64 * 72];                  // [dim(64)][key(64)] stride 72
    __shared__ u16 PbH[4 * 16 * 56];             // per-wave P, row stride 56

    int sidx_i = blockIdx.z + zofs;
    int lgC = 8 - 2 * sidx_i;                    // C = 256,64,16
    const int* sxb = sidx_base + sidx_i * BDIM * NTOK;
    float* out = (sidx_i == 0) ? out0 : (sidx_i == 1) ? out1 : out2;

    int t = threadIdx.x;
    int lane = t & 63, wave = t >> 6;
    int quad = lane >> 4, l16 = lane & 15;
    int bh = blockIdx.y, b = bh >> 4, h = bh & 15;
    int p0 = blockIdx.x * 128;
    sxb += b * NTOK;

    int ptile[2], ws_[2], we_[2];
    bf16x8 qhf[2][2], qlf[2][2];
#pragma unroll
    for (int tq = 0; tq < 2; ++tq) {
        ptile[tq] = p0 + wave * 32 + tq * 16;
        int c = ptile[tq] >> lgC;
        ws_[tq] = (c > 0) ? (c - 1) << lgC : 0;
        we_[tq] = (c + 1) << lgC;
        int qrow = sxb[ptile[tq] + l16];
        size_t rb = (size_t)(b * NTOK + qrow) * EDIM + h * HDIM + quad * 8;
#pragma unroll
        for (int kk = 0; kk < 2; ++kk) {
            qhf[tq][kk] = *(const bf16x8*)(Qh + rb + kk * 32);
            qlf[tq][kk] = *(const bf16x8*)(Ql + rb + kk * 32);
        }
    }

    f32x4 oacc[2][4] = {};
    float lpart[2][4] = {};
    float mrun[2] = {-1e30f, -1e30f};

    int c0 = p0 >> lgC, c1 = (p0 + 127) >> lgC;
    int kmin = (c0 > 0) ? (c0 - 1) << lgC : 0;
    int kmax = (c1 + 1) << lgC;
    int nsteps = (kmax - kmin + 63) >> 6;

    // ---- prologue: stage step 0 ----
    {
        int tok = sxb[min(kmin + wave * 16 + l16, NTOK - 1)];
        size_t rb = (size_t)(b * NTOK + tok) * EDIM + h * HDIM + quad * 8;
        GLL(Kh + rb,      &KfH[0][(wave * 2 + 0) * 512]);
        GLL(Kh + rb + 32, &KfH[0][(wave * 2 + 1) * 512]);
        GLL(Kl + rb,      &KfL[0][(wave * 2 + 0) * 512]);
        GLL(Kl + rb + 32, &KfL[0][(wave * 2 + 1) * 512]);
        bf16x8 vreg[2];
#pragma unroll
        for (int it = 0; it < 2; ++it) {
            int c = it * 256 + t;
            int key = c & 63, dg = c >> 6;
            int tok2 = sxb[min(kmin + key, NTOK - 1)];
            vreg[it] = *(const bf16x8*)(Vh + (size_t)(b * NTOK + tok2) * EDIM + h * HDIM + dg * 8);
        }
#pragma unroll
        for (int it = 0; it < 2; ++it) {
            int c = it * 256 + t;
            int key = c & 63, dg = c >> 6;
#pragma unroll
            for (int e = 0; e < 8; ++e)
                VL[(dg * 8 + e) * 72 + key] = (u16)vreg[it][e];
        }
        asm volatile("s_waitcnt vmcnt(0)" ::: "memory");
        __syncthreads();
    }

    int pb = 0;
    for (int s = 0; s < nsteps; ++s) {
        int ks = kmin + s * 64;
        int nk = min(64, kmax - ks);
        bool pf = (s + 1) < nsteps;
        bf16x8 vreg[2];
        if (pf) {
            int ks2 = ks + 64;
            int tok = sxb[min(ks2 + wave * 16 + l16, NTOK - 1)];
            size_t rb = (size_t)(b * NTOK + tok) * EDIM + h * HDIM + quad * 8;
            GLL(Kh + rb,      &KfH[pb ^ 1][(wave * 2 + 0) * 512]);
            GLL(Kh + rb + 32, &KfH[pb ^ 1][(wave * 2 + 1) * 512]);
            GLL(Kl + rb,      &KfL[pb ^ 1][(wave * 2 + 0) * 512]);
            GLL(Kl + rb + 32, &KfL[pb ^ 1][(wave * 2 + 1) * 512]);
#pragma unroll
            for (int it = 0; it < 2; ++it) {
                int c = it * 256 + t;
                int key = c & 63, dg = c >> 6;
                int tok2 = sxb[min(ks2 + key, NTOK - 1)];
                vreg[it] = *(const bf16x8*)(Vh + (size_t)(b * NTOK + tok2) * EDIM + h * HDIM + dg * 8);
            }
        }

        // ---- compute step s from KfH[pb]/KfL[pb] + VL ----
        int jlo0 = max(ks, ws_[0]) - ks, jhi0 = min(ks + nk, we_[0]) - ks;
        int jlo1 = max(ks, ws_[1]) - ks, jhi1 = min(ks + nk, we_[1]) - ks;
        bool e0 = jlo0 < jhi0, e1 = jlo1 < jhi1;
        if (e0 || e1) {
            int glo = e0 ? (e1 ? min(jlo0, jlo1) : jlo0) : jlo1;
            int ghi = e0 ? (e1 ? max(jhi0, jhi1) : jhi0) : jhi1;
            const u16* kfh = &KfH[pb][0];
            const u16* kfl = &KfL[pb][0];

            for (int g0 = glo & ~31; g0 < ghi; g0 += 32) {
                int s0i = g0 >> 4;
                int s1i = min(s0i + 1, 3);
                bf16x8 kh0[2], kl0[2], kh1[2], kl1[2];
#pragma unroll
                for (int kk = 0; kk < 2; ++kk) {
                    kh0[kk] = *(const bf16x8*)(kfh + ((s0i * 2 + kk) * 64 + lane) * 8);
                    kl0[kk] = *(const bf16x8*)(kfl + ((s0i * 2 + kk) * 64 + lane) * 8);
                    kh1[kk] = *(const bf16x8*)(kfh + ((s1i * 2 + kk) * 64 + lane) * 8);
                    kl1[kk] = *(const bf16x8*)(kfl + ((s1i * 2 + kk) * 64 + lane) * 8);
                }
#pragma unroll
                for (int tq = 0; tq < 2; ++tq) {
                    int jl = tq ? jlo1 : jlo0, jh = tq ? jhi1 : jhi0;
                    bool v0 = (g0 >= jl) && (g0 < jh);
                    bool v1 = (g0 + 16 >= jl) && (g0 + 16 < jh);
                    if (!v0 && !v1) continue;
                    f32x4 sa = {0.f, 0.f, 0.f, 0.f}, sb2 = {0.f, 0.f, 0.f, 0.f};
                    SETPRIO(1);
                    if (v0) {
                        sa = MFMA(qhf[tq][0], kh0[0], sa);
                        sa = MFMA(qhf[tq][0], kl0[0], sa);
                        sa = MFMA(qlf[tq][0], kh0[0], sa);
                        sa = MFMA(qhf[tq][1], kh0[1], sa);
                        sa = MFMA(qhf[tq][1], kl0[1], sa);
                        sa = MFMA(qlf[tq][1], kh0[1], sa);
                    }
                    if (v1) {
                        sb2 = MFMA(qhf[tq][0], kh1[0], sb2);
                        sb2 = MFMA(qhf[tq][0], kl1[0], sb2);
                        sb2 = MFMA(qlf[tq][0], kh1[0], sb2);
                        sb2 = MFMA(qhf[tq][1], kh1[1], sb2);
                        sb2 = MFMA(qhf[tq][1], kl1[1], sb2);
                        sb2 = MFMA(qlf[tq][1], kh1[1], sb2);
                    }
                    SETPRIO(0);
                    float smax = -1e30f;
                    if (v0) smax = fmaxf(smax, fmaxf(fmaxf(sa[0], sa[1]), fmaxf(sa[2], sa[3])));
                    if (v1) smax = fmaxf(smax, fmaxf(fmaxf(sb2[0], sb2[1]), fmaxf(sb2[2], sb2[3])));
                    smax = fmaxf(smax, __shfl_xor(smax, 1));
                    smax = fmaxf(smax, __shfl_xor(smax, 2));
                    smax = fmaxf(smax, __shfl_xor(smax, 4));
                    smax = fmaxf(smax, __shfl_xor(smax, 8));
                    float mold = mrun[tq];
                    float mnew = mold;
                    if (smax > mold + 8.0f) {      // T13 defer-max (THR=8)
                        mnew = smax;
                        mrun[tq] = mnew;
                        float alpha = __expf(mold - mnew);
#pragma unroll
                        for (int r = 0; r < 4; ++r) lpart[tq][r] *= alpha;
#pragma unroll
                        for (int dt = 0; dt < 4; ++dt) {
                            oacc[tq][dt][0] *= alpha; oacc[tq][dt][1] *= alpha;
                            oacc[tq][dt][2] *= alpha; oacc[tq][dt][3] *= alpha;
                        }
                    }
                    u16* pbh = PbH + wave * 896;
#pragma unroll
                    for (int r = 0; r < 4; ++r) {
                        float pa = v0 ? __expf(sa[r] - mnew) : 0.f;
                        float pbv = v1 ? __expf(sb2[r] - mnew) : 0.f;
                        lpart[tq][r] += pa + pbv;
                        pbh[(quad * 4 + r) * 56 + l16] = bf16rne(pa);
                        pbh[(quad * 4 + r) * 56 + 16 + l16] = bf16rne(pbv);
                    }
                    bf16x8 ph = *(const bf16x8*)(pbh + l16 * 56 + quad * 8);
                    int kh2 = g0 >> 5;
                    SETPRIO(1);
#pragma unroll
                    for (int dt = 0; dt < 4; ++dt) {
                        bf16x8 vv = *(const bf16x8*)(VL + (dt * 16 + l16) * 72 + kh2 * 32 + quad * 8);
                        oacc[tq][dt] = MFMA(ph, vv, oacc[tq][dt]);
                    }
                    SETPRIO(0);
                }
            }
        }

        asm volatile("s_waitcnt vmcnt(0)" ::: "memory");
        __syncthreads();                 // all waves done reading VL / K done
        if (pf) {
#pragma unroll
            for (int it = 0; it < 2; ++it) {
                int c = it * 256 + t;
                int key = c & 63, dg = c >> 6;
#pragma unroll
                for (int e = 0; e < 8; ++e)
                    VL[(dg * 8 + e) * 72 + key] = (u16)vreg[it][e];
            }
        }
        __syncthreads();                 // VL(t+1) ready
        pb ^= 1;
    }

#pragma unroll
    for (int tq = 0; tq < 2; ++tq) {
        float inv[4];
#pragma unroll
        for (int r = 0; r < 4; ++r) {
            float v = lpart[tq][r];
            v += __shfl_xor(v, 1);
            v += __shfl_xor(v, 2);
            v += __shfl_xor(v, 4);
            v += __shfl_xor(v, 8);
            inv[r] = 1.0f / (3.0f * v);
        }
#pragma unroll
        for (int r = 0; r < 4; ++r) {
            int tok = sxb[ptile[tq] + quad * 4 + r];
            size_t base = (size_t)(b * NTOK + tok) * EDIM + h * HDIM + l16;
            if (MODE == 2) {
#pragma unroll
                for (int dt = 0; dt < 4; ++dt) {
                    float v = out[base + dt * 16] + oacc[tq][dt][r] * inv[r];
                    u16 hh, ll;
                    split2(v, hh, ll);
                    osh[base + dt * 16] = hh;
                    osl[base + dt * 16] = ll;
                }
            } else if (MODE == 1) {
#pragma unroll
                for (int dt = 0; dt < 4; ++dt)
                    out[base + dt * 16] += oacc[tq][dt][r] * inv[r];
            } else {
#pragma unroll
                for (int dt = 0; dt < 4; ++dt)
                    out[base + dt * 16] = oacc[tq][dt][r] * inv[r];
            }
        }
    }
}

// ---------------------------------------------------------------------------
extern "C" void kernel_launch(void* const* d_in, const int* in_sizes, int n_in,
                              void* d_out, int out_size, void* d_ws, size_t ws_size,
                              hipStream_t stream)
{
    const float* x   = (const float*)d_in[0];
    const int*   wbc = (const int*)d_in[1];
    const int*   wbm = (const int*)d_in[2];
    const int*   wbf = (const int*)d_in[3];
    const float* Wq = (const float*)d_in[4],  *bq = (const float*)d_in[5];
    const float* Aq = (const float*)d_in[6],  *Bq = (const float*)d_in[7];
    const float* Wk = (const float*)d_in[8],  *bk = (const float*)d_in[9];
    const float* Ak = (const float*)d_in[10], *Bk = (const float*)d_in[11];
    const float* Wv = (const float*)d_in[12], *bv = (const float*)d_in[13];
    const float* Av = (const float*)d_in[14], *Bv = (const float*)d_in[15];
    const float* Wo = (const float*)d_in[16], *bo = (const float*)d_in[17];
    const float* Ao = (const float*)d_in[18], *Bo = (const float*)d_in[19];

    const size_t EE  = (size_t)EDIM * EDIM;        // 1,048,576
    const size_t BNE = (size_t)MROWS * EDIM;       // 8,388,608

    char* wsb = (char*)d_ws;
    float* ab = (float*)wsb;                        wsb += BNE * 4;   // attn scale-0
    u16* xh = (u16*)wsb;                            wsb += BNE * 2;   // x-split hi / abB lo half
    u16* xl = (u16*)wsb;                            wsb += BNE * 2;   // x-split lo / abB hi half
    u16* qh = (u16*)wsb;                            wsb += BNE * 2;
    u16* ql = (u16*)wsb;                            wsb += BNE * 2;
    u16* kh = (u16*)wsb;                            wsb += BNE * 2;
    u16* kl = (u16*)wsb;                            wsb += BNE * 2;
    u16* vh = (u16*)wsb;                            wsb += BNE * 2;
    u16* wh_all = (u16*)wsb;                        wsb += 3 * EE * 2; // [q|k|v] hi
    u16* wl_all = (u16*)wsb;                        wsb += 3 * EE * 2; // [q|k|v] lo
    u16* woh = (u16*)wsb;                           wsb += EE * 2;
    u16* wol = (u16*)wsb;                           wsb += EE * 2;
    int* sidx = (int*)wsb;                          wsb += 3 * BDIM * NTOK * 4;
    float* abC = (float*)wsb;                       // +BNE*4 if ws permits
    size_t need3 = (size_t)(wsb - (char*)d_ws) + BNE * 4;
    bool merged = (ws_size >= need3);

    split_kernel<<<BNE / 1024, 256, 0, stream>>>(x, xh, xl);

    build_weff4_kernel<<<dim3(4096, 4), 256, 0, stream>>>(
        Wq, Aq, Bq, Wk, Ak, Bk, Wv, Av, Bv, Wo, Ao, Bo,
        wh_all + 0 * EE, wl_all + 0 * EE,
        wh_all + 1 * EE, wl_all + 1 * EE,
        wh_all + 2 * EE, wl_all + 2 * EE,
        woh, wol);

    sort3_kernel<<<dim3(BDIM, 3), 256, 0, stream>>>(wbc, wbm, wbf, sidx);

    // QK projection (N = 2048, split-bf16 3-pass), 512 blocks x 512 thr
    gemm_qk_kernel<<<512, 512, 0, stream>>>(xh, xl, wh_all, wl_all,
                                            bq, bk, qh, ql, kh, kl);
    // V projection (N = 1024, 1-pass), 256 blocks x 512 thr
    gemm_v_kernel<<<256, 512, 0, stream>>>(xh, wh_all + 2 * EE, bv, vh);

    if (merged) {
        // all 3 scales CONCURRENT: each stores to its own f32 buffer.
        // abA = ab; abB overlays xh+xl (free after the QKV GEMMs); abC extra.
        float* abB = (float*)xh;
        dim3 ga3(NTOK / 128, BDIM * HEADS, 3);     // 3072 blocks
        attn_mfma_kernel<0><<<ga3, 256, 0, stream>>>(
            qh, ql, kh, kl, vh, sidx, 0, ab, abB, abC, nullptr, nullptr);
        // (abA + abB) + abC -> hi/lo split into qh/ql (free after attn)
        sumsplit3_kernel<<<BNE / 1024, 256, 0, stream>>>(ab, abB, abC, qh, ql);
        gemm_o_kernel<<<256, 512, 0, stream>>>(qh, ql, woh, wol, bo, (float*)d_out);
    } else {
        // serial fallback (r5-proven): store / acc / acc+split
        dim3 ga(NTOK / 128, BDIM * HEADS);
        attn_mfma_kernel<0><<<ga, 256, 0, stream>>>(
            qh, ql, kh, kl, vh, sidx, 0, ab, ab, ab, nullptr, nullptr);
        attn_mfma_kernel<1><<<ga, 256, 0, stream>>>(
            qh, ql, kh, kl, vh, sidx, 1, ab, ab, ab, nullptr, nullptr);
        attn_mfma_kernel<2><<<ga, 256, 0, stream>>>(
            qh, ql, kh, kl, vh, sidx, 2, ab, ab, ab, xh, xl);
        gemm_o_kernel<<<256, 512, 0, stream>>>(xh, xl, woh, wol, bo, (float*)d_out);
    }
}

// Round 8
// 477.295 us; speedup vs baseline: 1.0806x; 1.0088x over previous
//
#include <hip/hip_runtime.h>
#include <cstdint>
#include <cstddef>

// Problem constants
#define BDIM 2
#define NTOK 4096
#define EDIM 1024
#define HEADS 16
#define HDIM 64
#define MROWS (BDIM * NTOK)   // 8192

typedef unsigned short u16;
typedef __attribute__((ext_vector_type(8))) short bf16x8;   // 8 bf16 = 4 VGPR
typedef __attribute__((ext_vector_type(8))) unsigned short u16x8;
typedef __attribute__((ext_vector_type(4))) float f32x4;

#define MFMA(a, b, c) __builtin_amdgcn_mfma_f32_16x16x32_bf16(a, b, c, 0, 0, 0)
#define BAR() asm volatile("s_barrier" ::: "memory")
#define SETPRIO(p) __builtin_amdgcn_s_setprio(p)

// round-to-nearest-even split of fp32 into hi/lo bf16
__device__ inline void split2(float x, u16& h, u16& l) {
    union { float f; unsigned u; } a;
    a.f = x;
    unsigned uh = a.u + 0x7fff + ((a.u >> 16) & 1);
    h = (u16)(uh >> 16);
    union { unsigned u; float f; } hf; hf.u = (unsigned)h << 16;
    a.f = x - hf.f;
    unsigned ul = a.u + 0x7fff + ((a.u >> 16) & 1);
    l = (u16)(ul >> 16);
}

__device__ inline u16 bf16rne(float x) {
    union { float f; unsigned u; } a; a.f = x;
    unsigned r = a.u + 0x7fff + ((a.u >> 16) & 1);
    return (u16)(r >> 16);
}

// global -> LDS direct 16B staging (lane i lands at lds_base + i*16)
#define GLL(gp, lp) __builtin_amdgcn_global_load_lds( \
    (const __attribute__((address_space(1))) unsigned*)(gp), \
    (__attribute__((address_space(3))) unsigned*)(lp), 16, 0, 0)

// ---------------------------------------------------------------------------
// W_eff = W + 2*B@A for all 4 projections in one launch. grid=(4096,4)
// ---------------------------------------------------------------------------
__global__ __launch_bounds__(256) void build_weff4_kernel(
    const float* __restrict__ W0, const float* __restrict__ A0, const float* __restrict__ B0,
    const float* __restrict__ W1, const float* __restrict__ A1, const float* __restrict__ B1,
    const float* __restrict__ W2, const float* __restrict__ A2, const float* __restrict__ B2,
    const float* __restrict__ W3, const float* __restrict__ A3, const float* __restrict__ B3,
    u16* __restrict__ dh0, u16* __restrict__ dl0,
    u16* __restrict__ dh1, u16* __restrict__ dl1,
    u16* __restrict__ dh2, u16* __restrict__ dl2,
    u16* __restrict__ dh3, u16* __restrict__ dl3)
{
    int s = blockIdx.y;
    const float* W = (s == 0) ? W0 : (s == 1) ? W1 : (s == 2) ? W2 : W3;
    const float* A = (s == 0) ? A0 : (s == 1) ? A1 : (s == 2) ? A2 : A3;
    const float* Bm = (s == 0) ? B0 : (s == 1) ? B1 : (s == 2) ? B2 : B3;
    u16* dh = (s == 0) ? dh0 : (s == 1) ? dh1 : (s == 2) ? dh2 : dh3;
    u16* dl = (s == 0) ? dl0 : (s == 1) ? dl1 : (s == 2) ? dl2 : dl3;

    int idx = blockIdx.x * 256 + threadIdx.x;      // over E*E
    int o = idx >> 10, i = idx & 1023;
    float sum = 0.f;
#pragma unroll
    for (int r = 0; r < 8; ++r) sum += Bm[o * 8 + r] * A[r * 1024 + i];
    float w = W[idx] + 2.0f * sum;
    u16 h, l;
    split2(w, h, l);
    dh[idx] = h; dl[idx] = l;
}

// ---------------------------------------------------------------------------
// fp32 buffer -> hi/lo bf16 buffers, 4 elements / thread
// ---------------------------------------------------------------------------
__global__ __launch_bounds__(256) void split_kernel(
    const float* __restrict__ src, u16* __restrict__ dh, u16* __restrict__ dl)
{
    int idx = blockIdx.x * 256 + threadIdx.x;      // one float4
    float4 v = ((const float4*)src)[idx];
    ushort4 h, l;
    split2(v.x, h.x, l.x);
    split2(v.y, h.y, l.y);
    split2(v.z, h.z, l.z);
    split2(v.w, h.w, l.w);
    ((ushort4*)dh)[idx] = h;
    ((ushort4*)dl)[idx] = l;
}

// ---------------------------------------------------------------------------
// (A + B + C) -> hi/lo bf16 split, 4 elements / thread (merged-attn path)
// ---------------------------------------------------------------------------
__global__ __launch_bounds__(256) void sumsplit3_kernel(
    const float* __restrict__ A, const float* __restrict__ B,
    const float* __restrict__ Cc, u16* __restrict__ dh, u16* __restrict__ dl)
{
    int idx = blockIdx.x * 256 + threadIdx.x;      // one float4
    float4 a = ((const float4*)A)[idx];
    float4 b = ((const float4*)B)[idx];
    float4 c = ((const float4*)Cc)[idx];
    float v[4] = {(a.x + b.x) + c.x, (a.y + b.y) + c.y,
                  (a.z + b.z) + c.z, (a.w + b.w) + c.w};
    ushort4 h, l;
    split2(v[0], h.x, l.x);
    split2(v[1], h.y, l.y);
    split2(v[2], h.z, l.z);
    split2(v[3], h.w, l.w);
    ((ushort4*)dh)[idx] = h;
    ((ushort4*)dl)[idx] = l;
}

// ---------------------------------------------------------------------------
// Parallel stable counting sort, 3 scales x BDIM batches. grid=(BDIM,3).
// ---------------------------------------------------------------------------
__global__ __launch_bounds__(256) void sort3_kernel(
    const int* __restrict__ w0, const int* __restrict__ w1,
    const int* __restrict__ w2, int* __restrict__ sidx)
{
    __shared__ int sb[NTOK];          // 16 KB
    __shared__ int cnt[32][256];      // 32 KB
    __shared__ int gb[256];           // 1 KB
    const int* srcs[3] = {w0, w1, w2};
    int t = threadIdx.x;
    const int* w = srcs[blockIdx.y] + blockIdx.x * NTOK;
    int* outp = sidx + ((int)blockIdx.y * BDIM + (int)blockIdx.x) * NTOK;

    for (int i = t; i < NTOK; i += 256) sb[i] = w[i];
    for (int i = t; i < 32 * 256; i += 256) ((int*)cnt)[i] = 0;
    __syncthreads();

    int g = t >> 3;
#pragma unroll
    for (int e = 0; e < 16; ++e)
        atomicAdd(&cnt[g][sb[g * 128 + (t & 7) + 8 * e]], 1);
    __syncthreads();

    int run = 0;
#pragma unroll
    for (int gg = 0; gg < 32; ++gg) {
        int c = cnt[gg][t];
        cnt[gg][t] = run;
        run += c;
    }
    gb[t] = run;
    __syncthreads();
    if (t == 0) {
        int acc = 0;
        for (int v = 0; v < 256; ++v) { int c = gb[v]; gb[v] = acc; acc += c; }
    }
    __syncthreads();
    for (int i = t; i < 32 * 256; i += 256) {
        int v = i & 255, gg = i >> 8;
        cnt[gg][v] += gb[v];
    }
    __syncthreads();

    if (t < 32) {
        int base = t * 128;
        for (int e = 0; e < 128; ++e) {
            int v = sb[base + e];
            int p = cnt[t][v]++;
            outp[p] = base + e;
        }
    }
}

// ---------------------------------------------------------------------------
// QK split-bf16 MFMA GEMM (3-pass). BM=256, BN=128, BK=32, 512 thr
// (8 waves of 64x64), 3 LDS buffers + counted vmcnt(6), 4-phase interleave
// (r5-proven: 117 us / 37% MfmaUtil). grid = 512.
// ---------------------------------------------------------------------------
__global__ __launch_bounds__(512, 2) void gemm_qk_kernel(
    const u16* __restrict__ Xh, const u16* __restrict__ Xl,
    const u16* __restrict__ Wh, const u16* __restrict__ Wl,
    const float* __restrict__ bq, const float* __restrict__ bk,
    u16* __restrict__ qh, u16* __restrict__ ql,
    u16* __restrict__ kh, u16* __restrict__ kl)
{
    __shared__ __align__(16) unsigned char smem[147456];  // 3 x 48 KB buffers
    u16* lds = (u16*)smem;
    const int PA_h = 0, PA_l = 8192, PB_h = 16384, PB_l = 20480;  // u16 units

    int t = threadIdx.x;
    int lane = t & 63, wave = t >> 6;
    int bid = blockIdx.x;
    int wg = (bid & 7) * 64 + (bid >> 3);   // XCD-bijective swizzle (512%8==0)
    int bx = wg & 15, by = wg >> 4;
    int m0 = by * 256, n0 = bx * 128;       // n0 in [0,2048)

    int lrow = lane & 15, lq = lane >> 4;
    size_t aoff = (size_t)(m0 + wave * 32 + lrow) * EDIM + lq * 8;
    size_t boff = (size_t)(n0 + wave * 16 + lrow) * EDIM + lq * 8;
    int slabA = wave * 2;
    int sA0 = (wave >> 1) * 4;
    int sB0 = (wave & 1) * 4;
    f32x4 acc[4][4] = {};

    // prologue: stage tiles 0 and 1
#pragma unroll
    for (int tt = 0; tt < 2; ++tt) {
        u16* sbuf = lds + tt * 24576;
        int kk = tt * 32;
        GLL(Xh + aoff + kk,             sbuf + PA_h + (slabA + 0) * 512);
        GLL(Xh + aoff + kk + 16 * EDIM, sbuf + PA_h + (slabA + 1) * 512);
        GLL(Xl + aoff + kk,             sbuf + PA_l + (slabA + 0) * 512);
        GLL(Xl + aoff + kk + 16 * EDIM, sbuf + PA_l + (slabA + 1) * 512);
        GLL(Wh + boff + kk, sbuf + PB_h + wave * 512);
        GLL(Wl + boff + kk, sbuf + PB_l + wave * 512);
    }
    asm volatile("s_waitcnt vmcnt(6)" ::: "memory");
    BAR();

    for (int t32 = 0; t32 < 32; ++t32) {
        u16* rb = lds + (t32 % 3) * 24576;
        u16* sbuf = lds + ((t32 + 2) % 3) * 24576;
        bool pf = (t32 + 2) < 32;
        int kn = (t32 + 2) * 32;
        bf16x8 bhf[4], blf[4];
#pragma unroll
        for (int p = 0; p < 4; ++p) {
            if (p == 0) {
#pragma unroll
                for (int j = 0; j < 4; ++j) {
                    bhf[j] = *(const bf16x8*)(rb + PB_h + (sB0 + j) * 512 + lane * 8);
                    blf[j] = *(const bf16x8*)(rb + PB_l + (sB0 + j) * 512 + lane * 8);
                }
            }
            bf16x8 aph = *(const bf16x8*)(rb + PA_h + (sA0 + p) * 512 + lane * 8);
            bf16x8 apl = *(const bf16x8*)(rb + PA_l + (sA0 + p) * 512 + lane * 8);
            if (pf) {
                if (p == 0) {
                    GLL(Xh + aoff + kn,             sbuf + PA_h + (slabA + 0) * 512);
                    GLL(Xh + aoff + kn + 16 * EDIM, sbuf + PA_h + (slabA + 1) * 512);
                } else if (p == 1) {
                    GLL(Xl + aoff + kn,             sbuf + PA_l + (slabA + 0) * 512);
                    GLL(Xl + aoff + kn + 16 * EDIM, sbuf + PA_l + (slabA + 1) * 512);
                } else if (p == 2) {
                    GLL(Wh + boff + kn, sbuf + PB_h + wave * 512);
                    GLL(Wl + boff + kn, sbuf + PB_l + wave * 512);
                }
            }
            BAR();
            SETPRIO(1);
#pragma unroll
            for (int j = 0; j < 4; ++j) {
                acc[p][j] = MFMA(aph, bhf[j], acc[p][j]);
                acc[p][j] = MFMA(aph, blf[j], acc[p][j]);
                acc[p][j] = MFMA(apl, bhf[j], acc[p][j]);
            }
            SETPRIO(0);
            if (p == 3) {
                if (pf) asm volatile("s_waitcnt vmcnt(6)" ::: "memory");
                else    asm volatile("s_waitcnt vmcnt(0)" ::: "memory");
            }
            BAR();
        }
    }

    // ---- epilogue: per-wave LDS repack -> coalesced u16x8 split stores ----
    int proj = n0 >> 10;                    // 0=Q, 1=K
    const float* bias = proj ? bk : bq;
    u16* ohp = proj ? kh : qh;
    u16* olp = proj ? kl : ql;
    int wm = (wave >> 1) * 64, wn = (wave & 1) * 64;
    int q4 = lane >> 4, l16 = lane & 15;
    int cb = (n0 & 1023) + wn;
    float bj[4];
#pragma unroll
    for (int j = 0; j < 4; ++j) bj[j] = bias[cb + j * 16 + l16];
    float* repw = (float*)smem + wave * 2176;   // 32 rows x stride 68
    int r8 = lane >> 3, c8 = lane & 7;
#pragma unroll
    for (int gph = 0; gph < 2; ++gph) {
#pragma unroll
        for (int ii = 0; ii < 2; ++ii)
#pragma unroll
            for (int j = 0; j < 4; ++j)
#pragma unroll
                for (int r = 0; r < 4; ++r)
                    repw[(ii * 16 + q4 * 4 + r) * 68 + j * 16 + l16] =
                        acc[gph * 2 + ii][j][r] + bj[j];
#pragma unroll
        for (int rg = 0; rg < 4; ++rg) {
            int lr = rg * 8 + r8;
            float4 f0 = *(float4*)(repw + lr * 68 + c8 * 8);
            float4 f1 = *(float4*)(repw + lr * 68 + c8 * 8 + 4);
            float fa[8] = {f0.x, f0.y, f0.z, f0.w, f1.x, f1.y, f1.z, f1.w};
            size_t off = (size_t)(m0 + wm + gph * 32 + lr) * EDIM + cb + c8 * 8;
            u16x8 hv, lv;
#pragma unroll
            for (int e = 0; e < 8; ++e) {
                float v = fa[e];
                if (proj == 0) v *= 0.125f;
                u16 hh, ll;
                split2(v, hh, ll);
                hv[e] = hh; lv[e] = ll;
            }
            *(u16x8*)(ohp + off) = hv;
            *(u16x8*)(olp + off) = lv;
        }
    }
}

// ---------------------------------------------------------------------------
// V projection GEMM (1-pass hi*hi). BM=256, BN=128, BK=32, 512 thr
// (8 waves of 64x64), 3 LDS buffers + counted vmcnt(3), 2-phase (r5-proven).
// grid = 256.
// ---------------------------------------------------------------------------
__global__ __launch_bounds__(512, 2) void gemm_v_kernel(
    const u16* __restrict__ Xh, const u16* __restrict__ Wv,
    const float* __restrict__ bv, u16* __restrict__ vh)
{
    __shared__ __align__(16) unsigned char smem[73728];   // 3 x 24 KB buffers
    u16* lds = (u16*)smem;

    int t = threadIdx.x;
    int lane = t & 63, wave = t >> 6;
    int bid = blockIdx.x;
    int wg = (bid & 7) * 32 + (bid >> 3);
    int bx = wg & 7, by = wg >> 3;
    int m0 = by * 256, nc0 = bx * 128;          // nc0: col within V's 1024

    int lrow = lane & 15, lq = lane >> 4;
    size_t aoff = (size_t)(m0 + wave * 32 + lrow) * EDIM + lq * 8;
    size_t boff = (size_t)(nc0 + wave * 16 + lrow) * EDIM + lq * 8;
    int slabA = wave * 2;
    int sA0 = (wave >> 1) * 4;                  // 4 m-frags
    int sB0 = (wave & 1) * 4;                   // 4 n-frags
    f32x4 acc[4][4] = {};

    // prologue: stage tiles 0 and 1
#pragma unroll
    for (int tt = 0; tt < 2; ++tt) {
        u16* sbuf = lds + tt * 12288;
        int kk = tt * 32;
        GLL(Xh + aoff + kk,             sbuf + (slabA + 0) * 512);
        GLL(Xh + aoff + kk + 16 * EDIM, sbuf + (slabA + 1) * 512);
        GLL(Wv + boff + kk,             sbuf + 8192 + wave * 512);
    }
    asm volatile("s_waitcnt vmcnt(3)" ::: "memory");
    BAR();

    for (int t32 = 0; t32 < 32; ++t32) {
        u16* rb = lds + (t32 % 3) * 12288;
        u16* sbuf = lds + ((t32 + 2) % 3) * 12288;
        bool pf = (t32 + 2) < 32;
        int kn = (t32 + 2) * 32;

        bf16x8 bhf[4];
#pragma unroll
        for (int j = 0; j < 4; ++j)
            bhf[j] = *(const bf16x8*)(rb + 8192 + (sB0 + j) * 512 + lane * 8);
        bf16x8 a0 = *(const bf16x8*)(rb + (sA0 + 0) * 512 + lane * 8);
        bf16x8 a1 = *(const bf16x8*)(rb + (sA0 + 1) * 512 + lane * 8);
        if (pf) {
            GLL(Xh + aoff + kn,             sbuf + (slabA + 0) * 512);
            GLL(Xh + aoff + kn + 16 * EDIM, sbuf + (slabA + 1) * 512);
        }
        BAR();
        SETPRIO(1);
#pragma unroll
        for (int j = 0; j < 4; ++j) {
            acc[0][j] = MFMA(a0, bhf[j], acc[0][j]);
            acc[1][j] = MFMA(a1, bhf[j], acc[1][j]);
        }
        SETPRIO(0);
        BAR();

        bf16x8 a2 = *(const bf16x8*)(rb + (sA0 + 2) * 512 + lane * 8);
        bf16x8 a3 = *(const bf16x8*)(rb + (sA0 + 3) * 512 + lane * 8);
        if (pf) GLL(Wv + boff + kn, sbuf + 8192 + wave * 512);
        BAR();
        SETPRIO(1);
#pragma unroll
        for (int j = 0; j < 4; ++j) {
            acc[2][j] = MFMA(a2, bhf[j], acc[2][j]);
            acc[3][j] = MFMA(a3, bhf[j], acc[3][j]);
        }
        SETPRIO(0);
        if (pf) asm volatile("s_waitcnt vmcnt(3)" ::: "memory");
        else    asm volatile("s_waitcnt vmcnt(0)" ::: "memory");
        BAR();
    }

    // ---- epilogue ----
    int wm = (wave >> 1) * 64, wn = (wave & 1) * 64;
    int q4 = lane >> 4, l16 = lane & 15;
    int cb = nc0 + wn;
    float bj[4];
#pragma unroll
    for (int j = 0; j < 4; ++j) bj[j] = bv[cb + j * 16 + l16];
    float* repw = (float*)smem + wave * 2176;
    int r8 = lane >> 3, c8 = lane & 7;
#pragma unroll
    for (int gph = 0; gph < 2; ++gph) {
#pragma unroll
        for (int ii = 0; ii < 2; ++ii)
#pragma unroll
            for (int j = 0; j < 4; ++j)
#pragma unroll
                for (int r = 0; r < 4; ++r)
                    repw[(ii * 16 + q4 * 4 + r) * 68 + j * 16 + l16] =
                        acc[gph * 2 + ii][j][r] + bj[j];
#pragma unroll
        for (int rg = 0; rg < 4; ++rg) {
            int lr = rg * 8 + r8;
            float4 f0 = *(float4*)(repw + lr * 68 + c8 * 8);
            float4 f1 = *(float4*)(repw + lr * 68 + c8 * 8 + 4);
            float fa[8] = {f0.x, f0.y, f0.z, f0.w, f1.x, f1.y, f1.z, f1.w};
            size_t off = (size_t)(m0 + wm + gph * 32 + lr) * EDIM + cb + c8 * 8;
            u16x8 hv;
#pragma unroll
            for (int e = 0; e < 8; ++e) hv[e] = bf16rne(fa[e]);
            *(u16x8*)(vh + off) = hv;
        }
    }
}

// ---------------------------------------------------------------------------
// O projection GEMM (3-pass split), fp32 out. BM=256, BN=128, BK=32, 512 thr
// (8 waves of 64x64), 3 LDS buffers + counted vmcnt(6), 4-phase (r5-proven).
// grid = 256 (32x8 tiles).
// ---------------------------------------------------------------------------
__global__ __launch_bounds__(512, 2) void gemm_o_kernel(
    const u16* __restrict__ Xh, const u16* __restrict__ Xl,
    const u16* __restrict__ Wh, const u16* __restrict__ Wl,
    const float* __restrict__ bias, float* __restrict__ Y)
{
    __shared__ __align__(16) unsigned char smem[147456];  // 3 x 48 KB buffers
    u16* lds = (u16*)smem;
    const int PA_h = 0, PA_l = 8192, PB_h = 16384, PB_l = 20480;  // u16 units

    int t = threadIdx.x;
    int lane = t & 63, wave = t >> 6;
    int bid = blockIdx.x;
    int wg = (bid & 7) * 32 + (bid >> 3);   // bijective over 256 (256%8==0)
    int bx = wg & 7, by = wg >> 3;          // 8 N-tiles x 32 M-tiles
    int m0 = by * 256, n0 = bx * 128;

    int lrow = lane & 15, lq = lane >> 4;
    size_t aoff = (size_t)(m0 + wave * 32 + lrow) * EDIM + lq * 8;
    size_t boff = (size_t)(n0 + wave * 16 + lrow) * EDIM + lq * 8;
    int slabA = wave * 2;
    int sA0 = (wave >> 1) * 4;
    int sB0 = (wave & 1) * 4;
    f32x4 acc[4][4] = {};

    // prologue: stage tiles 0 and 1
#pragma unroll
    for (int tt = 0; tt < 2; ++tt) {
        u16* sbuf = lds + tt * 24576;
        int kk = tt * 32;
        GLL(Xh + aoff + kk,             sbuf + PA_h + (slabA + 0) * 512);
        GLL(Xh + aoff + kk + 16 * EDIM, sbuf + PA_h + (slabA + 1) * 512);
        GLL(Xl + aoff + kk,             sbuf + PA_l + (slabA + 0) * 512);
        GLL(Xl + aoff + kk + 16 * EDIM, sbuf + PA_l + (slabA + 1) * 512);
        GLL(Wh + boff + kk, sbuf + PB_h + wave * 512);
        GLL(Wl + boff + kk, sbuf + PB_l + wave * 512);
    }
    asm volatile("s_waitcnt vmcnt(6)" ::: "memory");
    BAR();

    for (int t32 = 0; t32 < 32; ++t32) {
        u16* rb = lds + (t32 % 3) * 24576;
        u16* sbuf = lds + ((t32 + 2) % 3) * 24576;
        bool pf = (t32 + 2) < 32;
        int kn = (t32 + 2) * 32;
        bf16x8 bhf[4], blf[4];
#pragma unroll
        for (int p = 0; p < 4; ++p) {
            if (p == 0) {
#pragma unroll
                for (int j = 0; j < 4; ++j) {
                    bhf[j] = *(const bf16x8*)(rb + PB_h + (sB0 + j) * 512 + lane * 8);
                    blf[j] = *(const bf16x8*)(rb + PB_l + (sB0 + j) * 512 + lane * 8);
                }
            }
            bf16x8 aph = *(const bf16x8*)(rb + PA_h + (sA0 + p) * 512 + lane * 8);
            bf16x8 apl = *(const bf16x8*)(rb + PA_l + (sA0 + p) * 512 + lane * 8);
            if (pf) {
                if (p == 0) {
                    GLL(Xh + aoff + kn,             sbuf + PA_h + (slabA + 0) * 512);
                    GLL(Xh + aoff + kn + 16 * EDIM, sbuf + PA_h + (slabA + 1) * 512);
                } else if (p == 1) {
                    GLL(Xl + aoff + kn,             sbuf + PA_l + (slabA + 0) * 512);
                    GLL(Xl + aoff + kn + 16 * EDIM, sbuf + PA_l + (slabA + 1) * 512);
                } else if (p == 2) {
                    GLL(Wh + boff + kn, sbuf + PB_h + wave * 512);
                    GLL(Wl + boff + kn, sbuf + PB_l + wave * 512);
                }
            }
            BAR();
            SETPRIO(1);
#pragma unroll
            for (int j = 0; j < 4; ++j) {
                acc[p][j] = MFMA(aph, bhf[j], acc[p][j]);
                acc[p][j] = MFMA(aph, blf[j], acc[p][j]);
                acc[p][j] = MFMA(apl, bhf[j], acc[p][j]);
            }
            SETPRIO(0);
            if (p == 3) {
                if (pf) asm volatile("s_waitcnt vmcnt(6)" ::: "memory");
                else    asm volatile("s_waitcnt vmcnt(0)" ::: "memory");
            }
            BAR();
        }
    }

    int wm = (wave >> 1) * 64, wn = (wave & 1) * 64;
    int col_in = lane & 15, rquad = lane >> 4;
#pragma unroll
    for (int j = 0; j < 4; ++j) {
        int col = n0 + wn + j * 16 + col_in;
        float bvv = bias[col];
#pragma unroll
        for (int i = 0; i < 4; ++i) {
            int mbase = m0 + wm + i * 16 + rquad * 4;
#pragma unroll
            for (int r = 0; r < 4; ++r)
                Y[(size_t)(mbase + r) * EDIM + col] = acc[i][j][r] + bvv;
        }
    }
}

// ---------------------------------------------------------------------------
// MFMA flash attention (r5-proven pipeline). Runtime scale s selects
// C = 256>>(2s) and the sidx slice; MODE: 0=store to per-scale buffer,
// 1=accumulate into out, 2=accumulate + fused hi/lo split epilogue.
// Merged path (grid.z=3, MODE=0): scales run CONCURRENTLY to separate
// buffers. bh-major XCD remap: all 96 blocks sharing one bh land on one
// XCD (linear id % 8), processed bh-sequentially -> K/V stays L2-resident
// (~2.5 MB working set < 4 MiB/XCD), killing the 4.5x cross-XCD re-fetch.
// ---------------------------------------------------------------------------
template <int MODE>
__global__ __launch_bounds__(256, 3) void attn_mfma_kernel(
    const u16* __restrict__ Qh, const u16* __restrict__ Ql,
    const u16* __restrict__ Kh, const u16* __restrict__ Kl,
    const u16* __restrict__ Vh, const int* __restrict__ sidx_base, int zofs,
    float* __restrict__ out0, float* __restrict__ out1, float* __restrict__ out2,
    u16* __restrict__ osh, u16* __restrict__ osl)
{
    __shared__ u16 KfH[2][4096], KfL[2][4096];   // dbuf K: [s(4)][kk(2)][lane][8]
    __shared__ u16 VL[64 * 72];                  // [dim(64)][key(64)] stride 72
    __shared__ u16 PbH[4 * 16 * 56];             // per-wave P, row stride 56

    int bx_, bh_, bz_;
    if (MODE == 0 && gridDim.z == 3) {
        // bh-major XCD remap over 3072 blocks (bijective):
        // xcd = lid&7 serves bh in {xcd, xcd+8, xcd+16, xcd+24}, 96 blocks each,
        // consecutive j within one bh -> XCD walks its bh values sequentially.
        int lid = blockIdx.x + (blockIdx.y << 5) + (blockIdx.z << 10);
        int xcd = lid & 7, j = lid >> 3;          // j in [0,384)
        bh_ = xcd + 8 * (j / 96);
        int rem = j % 96;
        bz_ = rem >> 5;
        bx_ = rem & 31;
    } else {
        bx_ = blockIdx.x; bh_ = blockIdx.y; bz_ = blockIdx.z;
    }

    int sidx_i = bz_ + zofs;
    int lgC = 8 - 2 * sidx_i;                    // C = 256,64,16
    const int* sxb = sidx_base + sidx_i * BDIM * NTOK;
    float* out = (sidx_i == 0) ? out0 : (sidx_i == 1) ? out1 : out2;

    int t = threadIdx.x;
    int lane = t & 63, wave = t >> 6;
    int quad = lane >> 4, l16 = lane & 15;
    int b = bh_ >> 4, h = bh_ & 15;
    int p0 = bx_ * 128;
    sxb += b * NTOK;

    int ptile[2], ws_[2], we_[2];
    bf16x8 qhf[2][2], qlf[2][2];
#pragma unroll
    for (int tq = 0; tq < 2; ++tq) {
        ptile[tq] = p0 + wave * 32 + tq * 16;
        int c = ptile[tq] >> lgC;
        ws_[tq] = (c > 0) ? (c - 1) << lgC : 0;
        we_[tq] = (c + 1) << lgC;
        int qrow = sxb[ptile[tq] + l16];
        size_t rb = (size_t)(b * NTOK + qrow) * EDIM + h * HDIM + quad * 8;
#pragma unroll
        for (int kk = 0; kk < 2; ++kk) {
            qhf[tq][kk] = *(const bf16x8*)(Qh + rb + kk * 32);
            qlf[tq][kk] = *(const bf16x8*)(Ql + rb + kk * 32);
        }
    }

    f32x4 oacc[2][4] = {};
    float lpart[2][4] = {};
    float mrun[2] = {-1e30f, -1e30f};

    int c0 = p0 >> lgC, c1 = (p0 + 127) >> lgC;
    int kmin = (c0 > 0) ? (c0 - 1) << lgC : 0;
    int kmax = (c1 + 1) << lgC;
    int nsteps = (kmax - kmin + 63) >> 6;

    // ---- prologue: stage step 0 ----
    {
        int tok = sxb[min(kmin + wave * 16 + l16, NTOK - 1)];
        size_t rb = (size_t)(b * NTOK + tok) * EDIM + h * HDIM + quad * 8;
        GLL(Kh + rb,      &KfH[0][(wave * 2 + 0) * 512]);
        GLL(Kh + rb + 32, &KfH[0][(wave * 2 + 1) * 512]);
        GLL(Kl + rb,      &KfL[0][(wave * 2 + 0) * 512]);
        GLL(Kl + rb + 32, &KfL[0][(wave * 2 + 1) * 512]);
        bf16x8 vreg[2];
#pragma unroll
        for (int it = 0; it < 2; ++it) {
            int c = it * 256 + t;
            int key = c & 63, dg = c >> 6;
            int tok2 = sxb[min(kmin + key, NTOK - 1)];
            vreg[it] = *(const bf16x8*)(Vh + (size_t)(b * NTOK + tok2) * EDIM + h * HDIM + dg * 8);
        }
#pragma unroll
        for (int it = 0; it < 2; ++it) {
            int c = it * 256 + t;
            int key = c & 63, dg = c >> 6;
#pragma unroll
            for (int e = 0; e < 8; ++e)
                VL[(dg * 8 + e) * 72 + key] = (u16)vreg[it][e];
        }
        asm volatile("s_waitcnt vmcnt(0)" ::: "memory");
        __syncthreads();
    }

    int pb = 0;
    for (int s = 0; s < nsteps; ++s) {
        int ks = kmin + s * 64;
        int nk = min(64, kmax - ks);
        bool pf = (s + 1) < nsteps;
        bf16x8 vreg[2];
        if (pf) {
            int ks2 = ks + 64;
            int tok = sxb[min(ks2 + wave * 16 + l16, NTOK - 1)];
            size_t rb = (size_t)(b * NTOK + tok) * EDIM + h * HDIM + quad * 8;
            GLL(Kh + rb,      &KfH[pb ^ 1][(wave * 2 + 0) * 512]);
            GLL(Kh + rb + 32, &KfH[pb ^ 1][(wave * 2 + 1) * 512]);
            GLL(Kl + rb,      &KfL[pb ^ 1][(wave * 2 + 0) * 512]);
            GLL(Kl + rb + 32, &KfL[pb ^ 1][(wave * 2 + 1) * 512]);
#pragma unroll
            for (int it = 0; it < 2; ++it) {
                int c = it * 256 + t;
                int key = c & 63, dg = c >> 6;
                int tok2 = sxb[min(ks2 + key, NTOK - 1)];
                vreg[it] = *(const bf16x8*)(Vh + (size_t)(b * NTOK + tok2) * EDIM + h * HDIM + dg * 8);
            }
        }

        // ---- compute step s from KfH[pb]/KfL[pb] + VL ----
        int jlo0 = max(ks, ws_[0]) - ks, jhi0 = min(ks + nk, we_[0]) - ks;
        int jlo1 = max(ks, ws_[1]) - ks, jhi1 = min(ks + nk, we_[1]) - ks;
        bool e0 = jlo0 < jhi0, e1 = jlo1 < jhi1;
        if (e0 || e1) {
            int glo = e0 ? (e1 ? min(jlo0, jlo1) : jlo0) : jlo1;
            int ghi = e0 ? (e1 ? max(jhi0, jhi1) : jhi0) : jhi1;
            const u16* kfh = &KfH[pb][0];
            const u16* kfl = &KfL[pb][0];

            for (int g0 = glo & ~31; g0 < ghi; g0 += 32) {
                int s0i = g0 >> 4;
                int s1i = min(s0i + 1, 3);
                bf16x8 kh0[2], kl0[2], kh1[2], kl1[2];
#pragma unroll
                for (int kk = 0; kk < 2; ++kk) {
                    kh0[kk] = *(const bf16x8*)(kfh + ((s0i * 2 + kk) * 64 + lane) * 8);
                    kl0[kk] = *(const bf16x8*)(kfl + ((s0i * 2 + kk) * 64 + lane) * 8);
                    kh1[kk] = *(const bf16x8*)(kfh + ((s1i * 2 + kk) * 64 + lane) * 8);
                    kl1[kk] = *(const bf16x8*)(kfl + ((s1i * 2 + kk) * 64 + lane) * 8);
                }
#pragma unroll
                for (int tq = 0; tq < 2; ++tq) {
                    int jl = tq ? jlo1 : jlo0, jh = tq ? jhi1 : jhi0;
                    bool v0 = (g0 >= jl) && (g0 < jh);
                    bool v1 = (g0 + 16 >= jl) && (g0 + 16 < jh);
                    if (!v0 && !v1) continue;
                    f32x4 sa = {0.f, 0.f, 0.f, 0.f}, sb2 = {0.f, 0.f, 0.f, 0.f};
                    SETPRIO(1);
                    if (v0) {
                        sa = MFMA(qhf[tq][0], kh0[0], sa);
                        sa = MFMA(qhf[tq][0], kl0[0], sa);
                        sa = MFMA(qlf[tq][0], kh0[0], sa);
                        sa = MFMA(qhf[tq][1], kh0[1], sa);
                        sa = MFMA(qhf[tq][1], kl0[1], sa);
                        sa = MFMA(qlf[tq][1], kh0[1], sa);
                    }
                    if (v1) {
                        sb2 = MFMA(qhf[tq][0], kh1[0], sb2);
                        sb2 = MFMA(qhf[tq][0], kl1[0], sb2);
                        sb2 = MFMA(qlf[tq][0], kh1[0], sb2);
                        sb2 = MFMA(qhf[tq][1], kh1[1], sb2);
                        sb2 = MFMA(qhf[tq][1], kl1[1], sb2);
                        sb2 = MFMA(qlf[tq][1], kh1[1], sb2);
                    }
                    SETPRIO(0);
                    float smax = -1e30f;
                    if (v0) smax = fmaxf(smax, fmaxf(fmaxf(sa[0], sa[1]), fmaxf(sa[2], sa[3])));
                    if (v1) smax = fmaxf(smax, fmaxf(fmaxf(sb2[0], sb2[1]), fmaxf(sb2[2], sb2[3])));
                    smax = fmaxf(smax, __shfl_xor(smax, 1));
                    smax = fmaxf(smax, __shfl_xor(smax, 2));
                    smax = fmaxf(smax, __shfl_xor(smax, 4));
                    smax = fmaxf(smax, __shfl_xor(smax, 8));
                    float mold = mrun[tq];
                    float mnew = mold;
                    if (smax > mold + 8.0f) {      // T13 defer-max (THR=8)
                        mnew = smax;
                        mrun[tq] = mnew;
                        float alpha = __expf(mold - mnew);
#pragma unroll
                        for (int r = 0; r < 4; ++r) lpart[tq][r] *= alpha;
#pragma unroll
                        for (int dt = 0; dt < 4; ++dt) {
                            oacc[tq][dt][0] *= alpha; oacc[tq][dt][1] *= alpha;
                            oacc[tq][dt][2] *= alpha; oacc[tq][dt][3] *= alpha;
                        }
                    }
                    u16* pbh = PbH + wave * 896;
#pragma unroll
                    for (int r = 0; r < 4; ++r) {
                        float pa = v0 ? __expf(sa[r] - mnew) : 0.f;
                        float pbv = v1 ? __expf(sb2[r] - mnew) : 0.f;
                        lpart[tq][r] += pa + pbv;
                        pbh[(quad * 4 + r) * 56 + l16] = bf16rne(pa);
                        pbh[(quad * 4 + r) * 56 + 16 + l16] = bf16rne(pbv);
                    }
                    bf16x8 ph = *(const bf16x8*)(pbh + l16 * 56 + quad * 8);
                    int kh2 = g0 >> 5;
                    SETPRIO(1);
#pragma unroll
                    for (int dt = 0; dt < 4; ++dt) {
                        bf16x8 vv = *(const bf16x8*)(VL + (dt * 16 + l16) * 72 + kh2 * 32 + quad * 8);
                        oacc[tq][dt] = MFMA(ph, vv, oacc[tq][dt]);
                    }
                    SETPRIO(0);
                }
            }
        }

        asm volatile("s_waitcnt vmcnt(0)" ::: "memory");
        __syncthreads();                 // all waves done reading VL / K done
        if (pf) {
#pragma unroll
            for (int it = 0; it < 2; ++it) {
                int c = it * 256 + t;
                int key = c & 63, dg = c >> 6;
#pragma unroll
                for (int e = 0; e < 8; ++e)
                    VL[(dg * 8 + e) * 72 + key] = (u16)vreg[it][e];
            }
        }
        __syncthreads();                 // VL(t+1) ready
        pb ^= 1;
    }

#pragma unroll
    for (int tq = 0; tq < 2; ++tq) {
        float inv[4];
#pragma unroll
        for (int r = 0; r < 4; ++r) {
            float v = lpart[tq][r];
            v += __shfl_xor(v, 1);
            v += __shfl_xor(v, 2);
            v += __shfl_xor(v, 4);
            v += __shfl_xor(v, 8);
            inv[r] = 1.0f / (3.0f * v);
        }
#pragma unroll
        for (int r = 0; r < 4; ++r) {
            int tok = sxb[ptile[tq] + quad * 4 + r];
            size_t base = (size_t)(b * NTOK + tok) * EDIM + h * HDIM + l16;
            if (MODE == 2) {
#pragma unroll
                for (int dt = 0; dt < 4; ++dt) {
                    float v = out[base + dt * 16] + oacc[tq][dt][r] * inv[r];
                    u16 hh, ll;
                    split2(v, hh, ll);
                    osh[base + dt * 16] = hh;
                    osl[base + dt * 16] = ll;
                }
            } else if (MODE == 1) {
#pragma unroll
                for (int dt = 0; dt < 4; ++dt)
                    out[base + dt * 16] += oacc[tq][dt][r] * inv[r];
            } else {
#pragma unroll
                for (int dt = 0; dt < 4; ++dt)
                    out[base + dt * 16] = oacc[tq][dt][r] * inv[r];
            }
        }
    }
}

// ---------------------------------------------------------------------------
extern "C" void kernel_launch(void* const* d_in, const int* in_sizes, int n_in,
                              void* d_out, int out_size, void* d_ws, size_t ws_size,
                              hipStream_t stream)
{
    const float* x   = (const float*)d_in[0];
    const int*   wbc = (const int*)d_in[1];
    const int*   wbm = (const int*)d_in[2];
    const int*   wbf = (const int*)d_in[3];
    const float* Wq = (const float*)d_in[4],  *bq = (const float*)d_in[5];
    const float* Aq = (const float*)d_in[6],  *Bq = (const float*)d_in[7];
    const float* Wk = (const float*)d_in[8],  *bk = (const float*)d_in[9];
    const float* Ak = (const float*)d_in[10], *Bk = (const float*)d_in[11];
    const float* Wv = (const float*)d_in[12], *bv = (const float*)d_in[13];
    const float* Av = (const float*)d_in[14], *Bv = (const float*)d_in[15];
    const float* Wo = (const float*)d_in[16], *bo = (const float*)d_in[17];
    const float* Ao = (const float*)d_in[18], *Bo = (const float*)d_in[19];

    const size_t EE  = (size_t)EDIM * EDIM;        // 1,048,576
    const size_t BNE = (size_t)MROWS * EDIM;       // 8,388,608

    char* wsb = (char*)d_ws;
    float* ab = (float*)wsb;                        wsb += BNE * 4;   // attn scale-0
    u16* xh = (u16*)wsb;                            wsb += BNE * 2;   // x-split hi / abB lo half
    u16* xl = (u16*)wsb;                            wsb += BNE * 2;   // x-split lo / abB hi half
    u16* qh = (u16*)wsb;                            wsb += BNE * 2;
    u16* ql = (u16*)wsb;                            wsb += BNE * 2;
    u16* kh = (u16*)wsb;                            wsb += BNE * 2;
    u16* kl = (u16*)wsb;                            wsb += BNE * 2;
    u16* vh = (u16*)wsb;                            wsb += BNE * 2;
    u16* wh_all = (u16*)wsb;                        wsb += 3 * EE * 2; // [q|k|v] hi
    u16* wl_all = (u16*)wsb;                        wsb += 3 * EE * 2; // [q|k|v] lo
    u16* woh = (u16*)wsb;                           wsb += EE * 2;
    u16* wol = (u16*)wsb;                           wsb += EE * 2;
    int* sidx = (int*)wsb;                          wsb += 3 * BDIM * NTOK * 4;
    float* abC = (float*)wsb;                       // +BNE*4 if ws permits
    size_t need3 = (size_t)(wsb - (char*)d_ws) + BNE * 4;
    bool merged = (ws_size >= need3);

    split_kernel<<<BNE / 1024, 256, 0, stream>>>(x, xh, xl);

    build_weff4_kernel<<<dim3(4096, 4), 256, 0, stream>>>(
        Wq, Aq, Bq, Wk, Ak, Bk, Wv, Av, Bv, Wo, Ao, Bo,
        wh_all + 0 * EE, wl_all + 0 * EE,
        wh_all + 1 * EE, wl_all + 1 * EE,
        wh_all + 2 * EE, wl_all + 2 * EE,
        woh, wol);

    sort3_kernel<<<dim3(BDIM, 3), 256, 0, stream>>>(wbc, wbm, wbf, sidx);

    // QK projection (N = 2048, split-bf16 3-pass), 512 blocks x 512 thr
    gemm_qk_kernel<<<512, 512, 0, stream>>>(xh, xl, wh_all, wl_all,
                                            bq, bk, qh, ql, kh, kl);
    // V projection (N = 1024, 1-pass), 256 blocks x 512 thr
    gemm_v_kernel<<<256, 512, 0, stream>>>(xh, wh_all + 2 * EE, bv, vh);

    if (merged) {
        // all 3 scales CONCURRENT: each stores to its own f32 buffer.
        // abA = ab; abB overlays xh+xl (free after the QKV GEMMs); abC extra.
        float* abB = (float*)xh;
        dim3 ga3(NTOK / 128, BDIM * HEADS, 3);     // 3072 blocks
        attn_mfma_kernel<0><<<ga3, 256, 0, stream>>>(
            qh, ql, kh, kl, vh, sidx, 0, ab, abB, abC, nullptr, nullptr);
        // (abA + abB) + abC -> hi/lo split into qh/ql (free after attn)
        sumsplit3_kernel<<<BNE / 1024, 256, 0, stream>>>(ab, abB, abC, qh, ql);
        gemm_o_kernel<<<256, 512, 0, stream>>>(qh, ql, woh, wol, bo, (float*)d_out);
    } else {
        // serial fallback (r5-proven): store / acc / acc+split
        dim3 ga(NTOK / 128, BDIM * HEADS);
        attn_mfma_kernel<0><<<ga, 256, 0, stream>>>(
            qh, ql, kh, kl, vh, sidx, 0, ab, ab, ab, nullptr, nullptr);
        attn_mfma_kernel<1><<<ga, 256, 0, stream>>>(
            qh, ql, kh, kl, vh, sidx, 1, ab, ab, ab, nullptr, nullptr);
        attn_mfma_kernel<2><<<ga, 256, 0, stream>>>(
            qh, ql, kh, kl, vh, sidx, 2, ab, ab, ab, xh, xl);
        gemm_o_kernel<<<256, 512, 0, stream>>>(xh, xl, woh, wol, bo, (float*)d_out);
    }
}

// Round 9
// 465.313 us; speedup vs baseline: 1.1084x; 1.0257x over previous
//
#include <hip/hip_runtime.h>
#include <cstdint>
#include <cstddef>

// Problem constants
#define BDIM 2
#define NTOK 4096
#define EDIM 1024
#define HEADS 16
#define HDIM 64
#define MROWS (BDIM * NTOK)   // 8192

typedef unsigned short u16;
typedef __attribute__((ext_vector_type(8))) short bf16x8;   // 8 bf16 = 4 VGPR
typedef __attribute__((ext_vector_type(8))) unsigned short u16x8;
typedef __attribute__((ext_vector_type(4))) float f32x4;

#define MFMA(a, b, c) __builtin_amdgcn_mfma_f32_16x16x32_bf16(a, b, c, 0, 0, 0)
#define BAR() asm volatile("s_barrier" ::: "memory")
#define SETPRIO(p) __builtin_amdgcn_s_setprio(p)

// round-to-nearest-even split of fp32 into hi/lo bf16
__device__ inline void split2(float x, u16& h, u16& l) {
    union { float f; unsigned u; } a;
    a.f = x;
    unsigned uh = a.u + 0x7fff + ((a.u >> 16) & 1);
    h = (u16)(uh >> 16);
    union { unsigned u; float f; } hf; hf.u = (unsigned)h << 16;
    a.f = x - hf.f;
    unsigned ul = a.u + 0x7fff + ((a.u >> 16) & 1);
    l = (u16)(ul >> 16);
}

__device__ inline u16 bf16rne(float x) {
    union { float f; unsigned u; } a; a.f = x;
    unsigned r = a.u + 0x7fff + ((a.u >> 16) & 1);
    return (u16)(r >> 16);
}

// global -> LDS direct 16B staging (lane i lands at lds_base + i*16)
#define GLL(gp, lp) __builtin_amdgcn_global_load_lds( \
    (const __attribute__((address_space(1))) unsigned*)(gp), \
    (__attribute__((address_space(3))) unsigned*)(lp), 16, 0, 0)

// ---------------------------------------------------------------------------
// PREP mega-kernel: sort3 (blocks 0-5) + x-split (6-8197) + weff4 (8198-24581)
// Pure concatenation of the three former kernels -> bit-identical outputs,
// 2 fewer launch boundaries. grid = 24582 x 256.
// ---------------------------------------------------------------------------
__global__ __launch_bounds__(256) void prep_kernel(
    const float* __restrict__ x, u16* __restrict__ xh, u16* __restrict__ xl,
    const int* __restrict__ w0, const int* __restrict__ w1,
    const int* __restrict__ w2, int* __restrict__ sidx,
    const float* __restrict__ W0, const float* __restrict__ A0, const float* __restrict__ B0,
    const float* __restrict__ W1, const float* __restrict__ A1, const float* __restrict__ B1,
    const float* __restrict__ W2, const float* __restrict__ A2, const float* __restrict__ B2,
    const float* __restrict__ W3, const float* __restrict__ A3, const float* __restrict__ B3,
    u16* __restrict__ dh0, u16* __restrict__ dl0,
    u16* __restrict__ dh1, u16* __restrict__ dl1,
    u16* __restrict__ dh2, u16* __restrict__ dl2,
    u16* __restrict__ dh3, u16* __restrict__ dl3)
{
    __shared__ int sb[NTOK];          // 16 KB  (sort branch only)
    __shared__ int cnt[32][256];      // 32 KB
    __shared__ int gb[256];           // 1 KB
    int bid = blockIdx.x;
    int t = threadIdx.x;

    if (bid < 6) {
        // ---- counting sort: by = scale (bid>>1), bx = batch (bid&1) ----
        int by = bid >> 1, bx = bid & 1;
        const int* srcs[3] = {w0, w1, w2};
        const int* w = srcs[by] + bx * NTOK;
        int* outp = sidx + ((int)by * BDIM + (int)bx) * NTOK;

        for (int i = t; i < NTOK; i += 256) sb[i] = w[i];
        for (int i = t; i < 32 * 256; i += 256) ((int*)cnt)[i] = 0;
        __syncthreads();

        int g = t >> 3;
#pragma unroll
        for (int e = 0; e < 16; ++e)
            atomicAdd(&cnt[g][sb[g * 128 + (t & 7) + 8 * e]], 1);
        __syncthreads();

        int run = 0;
#pragma unroll
        for (int gg = 0; gg < 32; ++gg) {
            int c = cnt[gg][t];
            cnt[gg][t] = run;
            run += c;
        }
        gb[t] = run;
        __syncthreads();
        if (t == 0) {
            int acc = 0;
            for (int v = 0; v < 256; ++v) { int c = gb[v]; gb[v] = acc; acc += c; }
        }
        __syncthreads();
        for (int i = t; i < 32 * 256; i += 256) {
            int v = i & 255, gg = i >> 8;
            cnt[gg][v] += gb[v];
        }
        __syncthreads();

        if (t < 32) {
            int base = t * 128;
            for (int e = 0; e < 128; ++e) {
                int v = sb[base + e];
                int p = cnt[t][v]++;
                outp[p] = base + e;
            }
        }
    } else if (bid < 8198) {
        // ---- x fp32 -> hi/lo bf16 split ----
        int idx = (bid - 6) * 256 + t;                 // one float4
        float4 v = ((const float4*)x)[idx];
        ushort4 h, l;
        split2(v.x, h.x, l.x);
        split2(v.y, h.y, l.y);
        split2(v.z, h.z, l.z);
        split2(v.w, h.w, l.w);
        ((ushort4*)xh)[idx] = h;
        ((ushort4*)xl)[idx] = l;
    } else {
        // ---- W_eff = W + 2*B@A, 4 projections ----
        int wid = bid - 8198;                          // [0, 16384)
        int s = wid >> 12, bx = wid & 4095;
        const float* W = (s == 0) ? W0 : (s == 1) ? W1 : (s == 2) ? W2 : W3;
        const float* A = (s == 0) ? A0 : (s == 1) ? A1 : (s == 2) ? A2 : A3;
        const float* Bm = (s == 0) ? B0 : (s == 1) ? B1 : (s == 2) ? B2 : B3;
        u16* dh = (s == 0) ? dh0 : (s == 1) ? dh1 : (s == 2) ? dh2 : dh3;
        u16* dl = (s == 0) ? dl0 : (s == 1) ? dl1 : (s == 2) ? dl2 : dl3;

        int idx = bx * 256 + t;                        // over E*E
        int o = idx >> 10, i = idx & 1023;
        float sum = 0.f;
#pragma unroll
        for (int r = 0; r < 8; ++r) sum += Bm[o * 8 + r] * A[r * 1024 + i];
        float w = W[idx] + 2.0f * sum;
        u16 h, l;
        split2(w, h, l);
        dh[idx] = h; dl[idx] = l;
    }
}

// ---------------------------------------------------------------------------
// (A + B + C) -> hi/lo bf16 split, 4 elements / thread (merged-attn path)
// ---------------------------------------------------------------------------
__global__ __launch_bounds__(256) void sumsplit3_kernel(
    const float* __restrict__ A, const float* __restrict__ B,
    const float* __restrict__ Cc, u16* __restrict__ dh, u16* __restrict__ dl)
{
    int idx = blockIdx.x * 256 + threadIdx.x;      // one float4
    float4 a = ((const float4*)A)[idx];
    float4 b = ((const float4*)B)[idx];
    float4 c = ((const float4*)Cc)[idx];
    float v[4] = {(a.x + b.x) + c.x, (a.y + b.y) + c.y,
                  (a.z + b.z) + c.z, (a.w + b.w) + c.w};
    ushort4 h, l;
    split2(v[0], h.x, l.x);
    split2(v[1], h.y, l.y);
    split2(v[2], h.z, l.z);
    split2(v[3], h.w, l.w);
    ((ushort4*)dh)[idx] = h;
    ((ushort4*)dl)[idx] = l;
}

// ---------------------------------------------------------------------------
// fp32 buffer -> hi/lo bf16 buffers (serial-fallback path only)
// ---------------------------------------------------------------------------
__global__ __launch_bounds__(256) void split_kernel(
    const float* __restrict__ src, u16* __restrict__ dh, u16* __restrict__ dl)
{
    int idx = blockIdx.x * 256 + threadIdx.x;      // one float4
    float4 v = ((const float4*)src)[idx];
    ushort4 h, l;
    split2(v.x, h.x, l.x);
    split2(v.y, h.y, l.y);
    split2(v.z, h.z, l.z);
    split2(v.w, h.w, l.w);
    ((ushort4*)dh)[idx] = h;
    ((ushort4*)dl)[idx] = l;
}

// ---------------------------------------------------------------------------
// Merged QKV GEMM: blocks 0-255 = V projection (1-pass, r5 2-phase schedule),
// blocks 256-767 = QK projection (3-pass, r5 4-phase schedule). v-first so
// qk's bid%8 XCD mapping is identical to the standalone kernel (256%8==0);
// CUs finishing short v blocks immediately pull qk work -> no drain barrier.
// 512 thr, LDS 144 KB static (v uses 72 KB of it).
// ---------------------------------------------------------------------------
__global__ __launch_bounds__(512, 2) void gemm_qkv_kernel(
    const u16* __restrict__ Xh, const u16* __restrict__ Xl,
    const u16* __restrict__ Wh, const u16* __restrict__ Wl,
    const u16* __restrict__ Wvh,
    const float* __restrict__ bq, const float* __restrict__ bk,
    const float* __restrict__ bv,
    u16* __restrict__ qh, u16* __restrict__ ql,
    u16* __restrict__ kh, u16* __restrict__ kl, u16* __restrict__ vh)
{
    __shared__ __align__(16) unsigned char smem[147456];
    u16* lds = (u16*)smem;
    int t = threadIdx.x;
    int lane = t & 63, wave = t >> 6;
    int bid = blockIdx.x;

    if (bid < 256) {
        // ================= V projection (BM=256, BN=128, 1-pass) ==========
        int wg = (bid & 7) * 32 + (bid >> 3);
        int bx = wg & 7, by = wg >> 3;
        int m0 = by * 256, nc0 = bx * 128;

        int lrow = lane & 15, lq = lane >> 4;
        size_t aoff = (size_t)(m0 + wave * 32 + lrow) * EDIM + lq * 8;
        size_t boff = (size_t)(nc0 + wave * 16 + lrow) * EDIM + lq * 8;
        int slabA = wave * 2;
        int sA0 = (wave >> 1) * 4;
        int sB0 = (wave & 1) * 4;
        f32x4 acc[4][4] = {};

#pragma unroll
        for (int tt = 0; tt < 2; ++tt) {
            u16* sbuf = lds + tt * 12288;
            int kk = tt * 32;
            GLL(Xh + aoff + kk,             sbuf + (slabA + 0) * 512);
            GLL(Xh + aoff + kk + 16 * EDIM, sbuf + (slabA + 1) * 512);
            GLL(Wvh + boff + kk,            sbuf + 8192 + wave * 512);
        }
        asm volatile("s_waitcnt vmcnt(3)" ::: "memory");
        BAR();

        for (int t32 = 0; t32 < 32; ++t32) {
            u16* rb = lds + (t32 % 3) * 12288;
            u16* sbuf = lds + ((t32 + 2) % 3) * 12288;
            bool pf = (t32 + 2) < 32;
            int kn = (t32 + 2) * 32;

            bf16x8 bhf[4];
#pragma unroll
            for (int j = 0; j < 4; ++j)
                bhf[j] = *(const bf16x8*)(rb + 8192 + (sB0 + j) * 512 + lane * 8);
            bf16x8 a0 = *(const bf16x8*)(rb + (sA0 + 0) * 512 + lane * 8);
            bf16x8 a1 = *(const bf16x8*)(rb + (sA0 + 1) * 512 + lane * 8);
            if (pf) {
                GLL(Xh + aoff + kn,             sbuf + (slabA + 0) * 512);
                GLL(Xh + aoff + kn + 16 * EDIM, sbuf + (slabA + 1) * 512);
            }
            BAR();
            SETPRIO(1);
#pragma unroll
            for (int j = 0; j < 4; ++j) {
                acc[0][j] = MFMA(a0, bhf[j], acc[0][j]);
                acc[1][j] = MFMA(a1, bhf[j], acc[1][j]);
            }
            SETPRIO(0);
            BAR();

            bf16x8 a2 = *(const bf16x8*)(rb + (sA0 + 2) * 512 + lane * 8);
            bf16x8 a3 = *(const bf16x8*)(rb + (sA0 + 3) * 512 + lane * 8);
            if (pf) GLL(Wvh + boff + kn, sbuf + 8192 + wave * 512);
            BAR();
            SETPRIO(1);
#pragma unroll
            for (int j = 0; j < 4; ++j) {
                acc[2][j] = MFMA(a2, bhf[j], acc[2][j]);
                acc[3][j] = MFMA(a3, bhf[j], acc[3][j]);
            }
            SETPRIO(0);
            if (pf) asm volatile("s_waitcnt vmcnt(3)" ::: "memory");
            else    asm volatile("s_waitcnt vmcnt(0)" ::: "memory");
            BAR();
        }

        int wm = (wave >> 1) * 64, wn = (wave & 1) * 64;
        int q4 = lane >> 4, l16 = lane & 15;
        int cb = nc0 + wn;
        float bj[4];
#pragma unroll
        for (int j = 0; j < 4; ++j) bj[j] = bv[cb + j * 16 + l16];
        float* repw = (float*)smem + wave * 2176;
        int r8 = lane >> 3, c8 = lane & 7;
#pragma unroll
        for (int gph = 0; gph < 2; ++gph) {
#pragma unroll
            for (int ii = 0; ii < 2; ++ii)
#pragma unroll
                for (int j = 0; j < 4; ++j)
#pragma unroll
                    for (int r = 0; r < 4; ++r)
                        repw[(ii * 16 + q4 * 4 + r) * 68 + j * 16 + l16] =
                            acc[gph * 2 + ii][j][r] + bj[j];
#pragma unroll
            for (int rg = 0; rg < 4; ++rg) {
                int lr = rg * 8 + r8;
                float4 f0 = *(float4*)(repw + lr * 68 + c8 * 8);
                float4 f1 = *(float4*)(repw + lr * 68 + c8 * 8 + 4);
                float fa[8] = {f0.x, f0.y, f0.z, f0.w, f1.x, f1.y, f1.z, f1.w};
                size_t off = (size_t)(m0 + wm + gph * 32 + lr) * EDIM + cb + c8 * 8;
                u16x8 hv;
#pragma unroll
                for (int e = 0; e < 8; ++e) hv[e] = bf16rne(fa[e]);
                *(u16x8*)(vh + off) = hv;
            }
        }
    } else {
        // ================= QK projection (BM=256, BN=128, 3-pass) =========
        const int PA_h = 0, PA_l = 8192, PB_h = 16384, PB_l = 20480;
        int qidx = bid - 256;
        int wg = (qidx & 7) * 64 + (qidx >> 3);
        int bx = wg & 15, by = wg >> 4;
        int m0 = by * 256, n0 = bx * 128;

        int lrow = lane & 15, lq = lane >> 4;
        size_t aoff = (size_t)(m0 + wave * 32 + lrow) * EDIM + lq * 8;
        size_t boff = (size_t)(n0 + wave * 16 + lrow) * EDIM + lq * 8;
        int slabA = wave * 2;
        int sA0 = (wave >> 1) * 4;
        int sB0 = (wave & 1) * 4;
        f32x4 acc[4][4] = {};

#pragma unroll
        for (int tt = 0; tt < 2; ++tt) {
            u16* sbuf = lds + tt * 24576;
            int kk = tt * 32;
            GLL(Xh + aoff + kk,             sbuf + PA_h + (slabA + 0) * 512);
            GLL(Xh + aoff + kk + 16 * EDIM, sbuf + PA_h + (slabA + 1) * 512);
            GLL(Xl + aoff + kk,             sbuf + PA_l + (slabA + 0) * 512);
            GLL(Xl + aoff + kk + 16 * EDIM, sbuf + PA_l + (slabA + 1) * 512);
            GLL(Wh + boff + kk, sbuf + PB_h + wave * 512);
            GLL(Wl + boff + kk, sbuf + PB_l + wave * 512);
        }
        asm volatile("s_waitcnt vmcnt(6)" ::: "memory");
        BAR();

        for (int t32 = 0; t32 < 32; ++t32) {
            u16* rb = lds + (t32 % 3) * 24576;
            u16* sbuf = lds + ((t32 + 2) % 3) * 24576;
            bool pf = (t32 + 2) < 32;
            int kn = (t32 + 2) * 32;
            bf16x8 bhf[4], blf[4];
#pragma unroll
            for (int p = 0; p < 4; ++p) {
                if (p == 0) {
#pragma unroll
                    for (int j = 0; j < 4; ++j) {
                        bhf[j] = *(const bf16x8*)(rb + PB_h + (sB0 + j) * 512 + lane * 8);
                        blf[j] = *(const bf16x8*)(rb + PB_l + (sB0 + j) * 512 + lane * 8);
                    }
                }
                bf16x8 aph = *(const bf16x8*)(rb + PA_h + (sA0 + p) * 512 + lane * 8);
                bf16x8 apl = *(const bf16x8*)(rb + PA_l + (sA0 + p) * 512 + lane * 8);
                if (pf) {
                    if (p == 0) {
                        GLL(Xh + aoff + kn,             sbuf + PA_h + (slabA + 0) * 512);
                        GLL(Xh + aoff + kn + 16 * EDIM, sbuf + PA_h + (slabA + 1) * 512);
                    } else if (p == 1) {
                        GLL(Xl + aoff + kn,             sbuf + PA_l + (slabA + 0) * 512);
                        GLL(Xl + aoff + kn + 16 * EDIM, sbuf + PA_l + (slabA + 1) * 512);
                    } else if (p == 2) {
                        GLL(Wh + boff + kn, sbuf + PB_h + wave * 512);
                        GLL(Wl + boff + kn, sbuf + PB_l + wave * 512);
                    }
                }
                BAR();
                SETPRIO(1);
#pragma unroll
                for (int j = 0; j < 4; ++j) {
                    acc[p][j] = MFMA(aph, bhf[j], acc[p][j]);
                    acc[p][j] = MFMA(aph, blf[j], acc[p][j]);
                    acc[p][j] = MFMA(apl, bhf[j], acc[p][j]);
                }
                SETPRIO(0);
                if (p == 3) {
                    if (pf) asm volatile("s_waitcnt vmcnt(6)" ::: "memory");
                    else    asm volatile("s_waitcnt vmcnt(0)" ::: "memory");
                }
                BAR();
            }
        }

        int proj = n0 >> 10;                    // 0=Q, 1=K
        const float* bias = proj ? bk : bq;
        u16* ohp = proj ? kh : qh;
        u16* olp = proj ? kl : ql;
        int wm = (wave >> 1) * 64, wn = (wave & 1) * 64;
        int q4 = lane >> 4, l16 = lane & 15;
        int cb = (n0 & 1023) + wn;
        float bj[4];
#pragma unroll
        for (int j = 0; j < 4; ++j) bj[j] = bias[cb + j * 16 + l16];
        float* repw = (float*)smem + wave * 2176;
        int r8 = lane >> 3, c8 = lane & 7;
#pragma unroll
        for (int gph = 0; gph < 2; ++gph) {
#pragma unroll
            for (int ii = 0; ii < 2; ++ii)
#pragma unroll
                for (int j = 0; j < 4; ++j)
#pragma unroll
                    for (int r = 0; r < 4; ++r)
                        repw[(ii * 16 + q4 * 4 + r) * 68 + j * 16 + l16] =
                            acc[gph * 2 + ii][j][r] + bj[j];
#pragma unroll
            for (int rg = 0; rg < 4; ++rg) {
                int lr = rg * 8 + r8;
                float4 f0 = *(float4*)(repw + lr * 68 + c8 * 8);
                float4 f1 = *(float4*)(repw + lr * 68 + c8 * 8 + 4);
                float fa[8] = {f0.x, f0.y, f0.z, f0.w, f1.x, f1.y, f1.z, f1.w};
                size_t off = (size_t)(m0 + wm + gph * 32 + lr) * EDIM + cb + c8 * 8;
                u16x8 hv, lv;
#pragma unroll
                for (int e = 0; e < 8; ++e) {
                    float v = fa[e];
                    if (proj == 0) v *= 0.125f;
                    u16 hh, ll;
                    split2(v, hh, ll);
                    hv[e] = hh; lv[e] = ll;
                }
                *(u16x8*)(ohp + off) = hv;
                *(u16x8*)(olp + off) = lv;
            }
        }
    }
}

// ---------------------------------------------------------------------------
// O projection GEMM (3-pass split), fp32 out. grid = 256 (32x8 tiles).
// ---------------------------------------------------------------------------
__global__ __launch_bounds__(512, 2) void gemm_o_kernel(
    const u16* __restrict__ Xh, const u16* __restrict__ Xl,
    const u16* __restrict__ Wh, const u16* __restrict__ Wl,
    const float* __restrict__ bias, float* __restrict__ Y)
{
    __shared__ __align__(16) unsigned char smem[147456];  // 3 x 48 KB buffers
    u16* lds = (u16*)smem;
    const int PA_h = 0, PA_l = 8192, PB_h = 16384, PB_l = 20480;  // u16 units

    int t = threadIdx.x;
    int lane = t & 63, wave = t >> 6;
    int bid = blockIdx.x;
    int wg = (bid & 7) * 32 + (bid >> 3);   // bijective over 256 (256%8==0)
    int bx = wg & 7, by = wg >> 3;          // 8 N-tiles x 32 M-tiles
    int m0 = by * 256, n0 = bx * 128;

    int lrow = lane & 15, lq = lane >> 4;
    size_t aoff = (size_t)(m0 + wave * 32 + lrow) * EDIM + lq * 8;
    size_t boff = (size_t)(n0 + wave * 16 + lrow) * EDIM + lq * 8;
    int slabA = wave * 2;
    int sA0 = (wave >> 1) * 4;
    int sB0 = (wave & 1) * 4;
    f32x4 acc[4][4] = {};

    // prologue: stage tiles 0 and 1
#pragma unroll
    for (int tt = 0; tt < 2; ++tt) {
        u16* sbuf = lds + tt * 24576;
        int kk = tt * 32;
        GLL(Xh + aoff + kk,             sbuf + PA_h + (slabA + 0) * 512);
        GLL(Xh + aoff + kk + 16 * EDIM, sbuf + PA_h + (slabA + 1) * 512);
        GLL(Xl + aoff + kk,             sbuf + PA_l + (slabA + 0) * 512);
        GLL(Xl + aoff + kk + 16 * EDIM, sbuf + PA_l + (slabA + 1) * 512);
        GLL(Wh + boff + kk, sbuf + PB_h + wave * 512);
        GLL(Wl + boff + kk, sbuf + PB_l + wave * 512);
    }
    asm volatile("s_waitcnt vmcnt(6)" ::: "memory");
    BAR();

    for (int t32 = 0; t32 < 32; ++t32) {
        u16* rb = lds + (t32 % 3) * 24576;
        u16* sbuf = lds + ((t32 + 2) % 3) * 24576;
        bool pf = (t32 + 2) < 32;
        int kn = (t32 + 2) * 32;
        bf16x8 bhf[4], blf[4];
#pragma unroll
        for (int p = 0; p < 4; ++p) {
            if (p == 0) {
#pragma unroll
                for (int j = 0; j < 4; ++j) {
                    bhf[j] = *(const bf16x8*)(rb + PB_h + (sB0 + j) * 512 + lane * 8);
                    blf[j] = *(const bf16x8*)(rb + PB_l + (sB0 + j) * 512 + lane * 8);
                }
            }
            bf16x8 aph = *(const bf16x8*)(rb + PA_h + (sA0 + p) * 512 + lane * 8);
            bf16x8 apl = *(const bf16x8*)(rb + PA_l + (sA0 + p) * 512 + lane * 8);
            if (pf) {
                if (p == 0) {
                    GLL(Xh + aoff + kn,             sbuf + PA_h + (slabA + 0) * 512);
                    GLL(Xh + aoff + kn + 16 * EDIM, sbuf + PA_h + (slabA + 1) * 512);
                } else if (p == 1) {
                    GLL(Xl + aoff + kn,             sbuf + PA_l + (slabA + 0) * 512);
                    GLL(Xl + aoff + kn + 16 * EDIM, sbuf + PA_l + (slabA + 1) * 512);
                } else if (p == 2) {
                    GLL(Wh + boff + kn, sbuf + PB_h + wave * 512);
                    GLL(Wl + boff + kn, sbuf + PB_l + wave * 512);
                }
            }
            BAR();
            SETPRIO(1);
#pragma unroll
            for (int j = 0; j < 4; ++j) {
                acc[p][j] = MFMA(aph, bhf[j], acc[p][j]);
                acc[p][j] = MFMA(aph, blf[j], acc[p][j]);
                acc[p][j] = MFMA(apl, bhf[j], acc[p][j]);
            }
            SETPRIO(0);
            if (p == 3) {
                if (pf) asm volatile("s_waitcnt vmcnt(6)" ::: "memory");
                else    asm volatile("s_waitcnt vmcnt(0)" ::: "memory");
            }
            BAR();
        }
    }

    int wm = (wave >> 1) * 64, wn = (wave & 1) * 64;
    int col_in = lane & 15, rquad = lane >> 4;
#pragma unroll
    for (int j = 0; j < 4; ++j) {
        int col = n0 + wn + j * 16 + col_in;
        float bvv = bias[col];
#pragma unroll
        for (int i = 0; i < 4; ++i) {
            int mbase = m0 + wm + i * 16 + rquad * 4;
#pragma unroll
            for (int r = 0; r < 4; ++r)
                Y[(size_t)(mbase + r) * EDIM + col] = acc[i][j][r] + bvv;
        }
    }
}

// ---------------------------------------------------------------------------
// MFMA flash attention (r5-proven pipeline + bh-major XCD remap, r8-proven
// FETCH 216->55 MB). Per-tq PbH buffers (stride 40) decouple the two q-tiles'
// P LDS round-trips so the compiler can overlap tq0-PV with tq1-QK.
// MODE: 0=store to per-scale buffer (merged, grid.z=3), 1=acc, 2=acc+split.
// ---------------------------------------------------------------------------
template <int MODE>
__global__ __launch_bounds__(256, 3) void attn_mfma_kernel(
    const u16* __restrict__ Qh, const u16* __restrict__ Ql,
    const u16* __restrict__ Kh, const u16* __restrict__ Kl,
    const u16* __restrict__ Vh, const int* __restrict__ sidx_base, int zofs,
    float* __restrict__ out0, float* __restrict__ out1, float* __restrict__ out2,
    u16* __restrict__ osh, u16* __restrict__ osl)
{
    __shared__ u16 KfH[2][4096], KfL[2][4096];   // dbuf K: [s(4)][kk(2)][lane][8]
    __shared__ u16 VL[64 * 72];                  // [dim(64)][key(64)] stride 72
    __shared__ u16 PbH[4 * 2 * 16 * 40];         // per-wave, per-tq P, stride 40

    int bx_, bh_, bz_;
    if (MODE == 0 && gridDim.z == 3) {
        int lid = blockIdx.x + (blockIdx.y << 5) + (blockIdx.z << 10);
        int xcd = lid & 7, j = lid >> 3;          // j in [0,384)
        bh_ = xcd + 8 * (j / 96);
        int rem = j % 96;
        bz_ = rem >> 5;
        bx_ = rem & 31;
    } else {
        bx_ = blockIdx.x; bh_ = blockIdx.y; bz_ = blockIdx.z;
    }

    int sidx_i = bz_ + zofs;
    int lgC = 8 - 2 * sidx_i;                    // C = 256,64,16
    const int* sxb = sidx_base + sidx_i * BDIM * NTOK;
    float* out = (sidx_i == 0) ? out0 : (sidx_i == 1) ? out1 : out2;

    int t = threadIdx.x;
    int lane = t & 63, wave = t >> 6;
    int quad = lane >> 4, l16 = lane & 15;
    int b = bh_ >> 4, h = bh_ & 15;
    int p0 = bx_ * 128;
    sxb += b * NTOK;

    int ptile[2], ws_[2], we_[2];
    bf16x8 qhf[2][2], qlf[2][2];
#pragma unroll
    for (int tq = 0; tq < 2; ++tq) {
        ptile[tq] = p0 + wave * 32 + tq * 16;
        int c = ptile[tq] >> lgC;
        ws_[tq] = (c > 0) ? (c - 1) << lgC : 0;
        we_[tq] = (c + 1) << lgC;
        int qrow = sxb[ptile[tq] + l16];
        size_t rb = (size_t)(b * NTOK + qrow) * EDIM + h * HDIM + quad * 8;
#pragma unroll
        for (int kk = 0; kk < 2; ++kk) {
            qhf[tq][kk] = *(const bf16x8*)(Qh + rb + kk * 32);
            qlf[tq][kk] = *(const bf16x8*)(Ql + rb + kk * 32);
        }
    }

    f32x4 oacc[2][4] = {};
    float lpart[2][4] = {};
    float mrun[2] = {-1e30f, -1e30f};

    int c0 = p0 >> lgC, c1 = (p0 + 127) >> lgC;
    int kmin = (c0 > 0) ? (c0 - 1) << lgC : 0;
    int kmax = (c1 + 1) << lgC;
    int nsteps = (kmax - kmin + 63) >> 6;

    // ---- prologue: stage step 0 ----
    {
        int tok = sxb[min(kmin + wave * 16 + l16, NTOK - 1)];
        size_t rb = (size_t)(b * NTOK + tok) * EDIM + h * HDIM + quad * 8;
        GLL(Kh + rb,      &KfH[0][(wave * 2 + 0) * 512]);
        GLL(Kh + rb + 32, &KfH[0][(wave * 2 + 1) * 512]);
        GLL(Kl + rb,      &KfL[0][(wave * 2 + 0) * 512]);
        GLL(Kl + rb + 32, &KfL[0][(wave * 2 + 1) * 512]);
        bf16x8 vreg[2];
#pragma unroll
        for (int it = 0; it < 2; ++it) {
            int c = it * 256 + t;
            int key = c & 63, dg = c >> 6;
            int tok2 = sxb[min(kmin + key, NTOK - 1)];
            vreg[it] = *(const bf16x8*)(Vh + (size_t)(b * NTOK + tok2) * EDIM + h * HDIM + dg * 8);
        }
#pragma unroll
        for (int it = 0; it < 2; ++it) {
            int c = it * 256 + t;
            int key = c & 63, dg = c >> 6;
#pragma unroll
            for (int e = 0; e < 8; ++e)
                VL[(dg * 8 + e) * 72 + key] = (u16)vreg[it][e];
        }
        asm volatile("s_waitcnt vmcnt(0)" ::: "memory");
        __syncthreads();
    }

    int pb = 0;
    for (int s = 0; s < nsteps; ++s) {
        int ks = kmin + s * 64;
        int nk = min(64, kmax - ks);
        bool pf = (s + 1) < nsteps;
        bf16x8 vreg[2];
        if (pf) {
            int ks2 = ks + 64;
            int tok = sxb[min(ks2 + wave * 16 + l16, NTOK - 1)];
            size_t rb = (size_t)(b * NTOK + tok) * EDIM + h * HDIM + quad * 8;
            GLL(Kh + rb,      &KfH[pb ^ 1][(wave * 2 + 0) * 512]);
            GLL(Kh + rb + 32, &KfH[pb ^ 1][(wave * 2 + 1) * 512]);
            GLL(Kl + rb,      &KfL[pb ^ 1][(wave * 2 + 0) * 512]);
            GLL(Kl + rb + 32, &KfL[pb ^ 1][(wave * 2 + 1) * 512]);
#pragma unroll
            for (int it = 0; it < 2; ++it) {
                int c = it * 256 + t;
                int key = c & 63, dg = c >> 6;
                int tok2 = sxb[min(ks2 + key, NTOK - 1)];
                vreg[it] = *(const bf16x8*)(Vh + (size_t)(b * NTOK + tok2) * EDIM + h * HDIM + dg * 8);
            }
        }

        // ---- compute step s from KfH[pb]/KfL[pb] + VL ----
        int jlo0 = max(ks, ws_[0]) - ks, jhi0 = min(ks + nk, we_[0]) - ks;
        int jlo1 = max(ks, ws_[1]) - ks, jhi1 = min(ks + nk, we_[1]) - ks;
        bool e0 = jlo0 < jhi0, e1 = jlo1 < jhi1;
        if (e0 || e1) {
            int glo = e0 ? (e1 ? min(jlo0, jlo1) : jlo0) : jlo1;
            int ghi = e0 ? (e1 ? max(jhi0, jhi1) : jhi0) : jhi1;
            const u16* kfh = &KfH[pb][0];
            const u16* kfl = &KfL[pb][0];

            for (int g0 = glo & ~31; g0 < ghi; g0 += 32) {
                int s0i = g0 >> 4;
                int s1i = min(s0i + 1, 3);
                bf16x8 kh0[2], kl0[2], kh1[2], kl1[2];
#pragma unroll
                for (int kk = 0; kk < 2; ++kk) {
                    kh0[kk] = *(const bf16x8*)(kfh + ((s0i * 2 + kk) * 64 + lane) * 8);
                    kl0[kk] = *(const bf16x8*)(kfl + ((s0i * 2 + kk) * 64 + lane) * 8);
                    kh1[kk] = *(const bf16x8*)(kfh + ((s1i * 2 + kk) * 64 + lane) * 8);
                    kl1[kk] = *(const bf16x8*)(kfl + ((s1i * 2 + kk) * 64 + lane) * 8);
                }
#pragma unroll
                for (int tq = 0; tq < 2; ++tq) {
                    int jl = tq ? jlo1 : jlo0, jh = tq ? jhi1 : jhi0;
                    bool v0 = (g0 >= jl) && (g0 < jh);
                    bool v1 = (g0 + 16 >= jl) && (g0 + 16 < jh);
                    if (!v0 && !v1) continue;
                    f32x4 sa = {0.f, 0.f, 0.f, 0.f}, sb2 = {0.f, 0.f, 0.f, 0.f};
                    SETPRIO(1);
                    if (v0) {
                        sa = MFMA(qhf[tq][0], kh0[0], sa);
                        sa = MFMA(qhf[tq][0], kl0[0], sa);
                        sa = MFMA(qlf[tq][0], kh0[0], sa);
                        sa = MFMA(qhf[tq][1], kh0[1], sa);
                        sa = MFMA(qhf[tq][1], kl0[1], sa);
                        sa = MFMA(qlf[tq][1], kh0[1], sa);
                    }
                    if (v1) {
                        sb2 = MFMA(qhf[tq][0], kh1[0], sb2);
                        sb2 = MFMA(qhf[tq][0], kl1[0], sb2);
                        sb2 = MFMA(qlf[tq][0], kh1[0], sb2);
                        sb2 = MFMA(qhf[tq][1], kh1[1], sb2);
                        sb2 = MFMA(qhf[tq][1], kl1[1], sb2);
                        sb2 = MFMA(qlf[tq][1], kh1[1], sb2);
                    }
                    SETPRIO(0);
                    float smax = -1e30f;
                    if (v0) smax = fmaxf(smax, fmaxf(fmaxf(sa[0], sa[1]), fmaxf(sa[2], sa[3])));
                    if (v1) smax = fmaxf(smax, fmaxf(fmaxf(sb2[0], sb2[1]), fmaxf(sb2[2], sb2[3])));
                    smax = fmaxf(smax, __shfl_xor(smax, 1));
                    smax = fmaxf(smax, __shfl_xor(smax, 2));
                    smax = fmaxf(smax, __shfl_xor(smax, 4));
                    smax = fmaxf(smax, __shfl_xor(smax, 8));
                    float mold = mrun[tq];
                    float mnew = mold;
                    if (smax > mold + 8.0f) {      // T13 defer-max (THR=8)
                        mnew = smax;
                        mrun[tq] = mnew;
                        float alpha = __expf(mold - mnew);
#pragma unroll
                        for (int r = 0; r < 4; ++r) lpart[tq][r] *= alpha;
#pragma unroll
                        for (int dt = 0; dt < 4; ++dt) {
                            oacc[tq][dt][0] *= alpha; oacc[tq][dt][1] *= alpha;
                            oacc[tq][dt][2] *= alpha; oacc[tq][dt][3] *= alpha;
                        }
                    }
                    u16* pbh = PbH + wave * 1280 + tq * 640;   // per-tq buffer
#pragma unroll
                    for (int r = 0; r < 4; ++r) {
                        float pa = v0 ? __expf(sa[r] - mnew) : 0.f;
                        float pbv = v1 ? __expf(sb2[r] - mnew) : 0.f;
                        lpart[tq][r] += pa + pbv;
                        pbh[(quad * 4 + r) * 40 + l16] = bf16rne(pa);
                        pbh[(quad * 4 + r) * 40 + 16 + l16] = bf16rne(pbv);
                    }
                    bf16x8 ph = *(const bf16x8*)(pbh + l16 * 40 + quad * 8);
                    int kh2 = g0 >> 5;
                    SETPRIO(1);
#pragma unroll
                    for (int dt = 0; dt < 4; ++dt) {
                        bf16x8 vv = *(const bf16x8*)(VL + (dt * 16 + l16) * 72 + kh2 * 32 + quad * 8);
                        oacc[tq][dt] = MFMA(ph, vv, oacc[tq][dt]);
                    }
                    SETPRIO(0);
                }
            }
        }

        asm volatile("s_waitcnt vmcnt(0)" ::: "memory");
        __syncthreads();                 // all waves done reading VL / K done
        if (pf) {
#pragma unroll
            for (int it = 0; it < 2; ++it) {
                int c = it * 256 + t;
                int key = c & 63, dg = c >> 6;
#pragma unroll
                for (int e = 0; e < 8; ++e)
                    VL[(dg * 8 + e) * 72 + key] = (u16)vreg[it][e];
            }
        }
        __syncthreads();                 // VL(t+1) ready
        pb ^= 1;
    }

#pragma unroll
    for (int tq = 0; tq < 2; ++tq) {
        float inv[4];
#pragma unroll
        for (int r = 0; r < 4; ++r) {
            float v = lpart[tq][r];
            v += __shfl_xor(v, 1);
            v += __shfl_xor(v, 2);
            v += __shfl_xor(v, 4);
            v += __shfl_xor(v, 8);
            inv[r] = 1.0f / (3.0f * v);
        }
#pragma unroll
        for (int r = 0; r < 4; ++r) {
            int tok = sxb[ptile[tq] + quad * 4 + r];
            size_t base = (size_t)(b * NTOK + tok) * EDIM + h * HDIM + l16;
            if (MODE == 2) {
#pragma unroll
                for (int dt = 0; dt < 4; ++dt) {
                    float v = out[base + dt * 16] + oacc[tq][dt][r] * inv[r];
                    u16 hh, ll;
                    split2(v, hh, ll);
                    osh[base + dt * 16] = hh;
                    osl[base + dt * 16] = ll;
                }
            } else if (MODE == 1) {
#pragma unroll
                for (int dt = 0; dt < 4; ++dt)
                    out[base + dt * 16] += oacc[tq][dt][r] * inv[r];
            } else {
#pragma unroll
                for (int dt = 0; dt < 4; ++dt)
                    out[base + dt * 16] = oacc[tq][dt][r] * inv[r];
            }
        }
    }
}

// ---------------------------------------------------------------------------
extern "C" void kernel_launch(void* const* d_in, const int* in_sizes, int n_in,
                              void* d_out, int out_size, void* d_ws, size_t ws_size,
                              hipStream_t stream)
{
    const float* x   = (const float*)d_in[0];
    const int*   wbc = (const int*)d_in[1];
    const int*   wbm = (const int*)d_in[2];
    const int*   wbf = (const int*)d_in[3];
    const float* Wq = (const float*)d_in[4],  *bq = (const float*)d_in[5];
    const float* Aq = (const float*)d_in[6],  *Bq = (const float*)d_in[7];
    const float* Wk = (const float*)d_in[8],  *bk = (const float*)d_in[9];
    const float* Ak = (const float*)d_in[10], *Bk = (const float*)d_in[11];
    const float* Wv = (const float*)d_in[12], *bv = (const float*)d_in[13];
    const float* Av = (const float*)d_in[14], *Bv = (const float*)d_in[15];
    const float* Wo = (const float*)d_in[16], *bo = (const float*)d_in[17];
    const float* Ao = (const float*)d_in[18], *Bo = (const float*)d_in[19];

    const size_t EE  = (size_t)EDIM * EDIM;        // 1,048,576
    const size_t BNE = (size_t)MROWS * EDIM;       // 8,388,608

    char* wsb = (char*)d_ws;
    float* ab = (float*)wsb;                        wsb += BNE * 4;   // attn scale-0
    u16* xh = (u16*)wsb;                            wsb += BNE * 2;   // x-split hi / abB lo half
    u16* xl = (u16*)wsb;                            wsb += BNE * 2;   // x-split lo / abB hi half
    u16* qh = (u16*)wsb;                            wsb += BNE * 2;
    u16* ql = (u16*)wsb;                            wsb += BNE * 2;
    u16* kh = (u16*)wsb;                            wsb += BNE * 2;
    u16* kl = (u16*)wsb;                            wsb += BNE * 2;
    u16* vh = (u16*)wsb;                            wsb += BNE * 2;
    u16* wh_all = (u16*)wsb;                        wsb += 3 * EE * 2; // [q|k|v] hi
    u16* wl_all = (u16*)wsb;                        wsb += 3 * EE * 2; // [q|k|v] lo
    u16* woh = (u16*)wsb;                           wsb += EE * 2;
    u16* wol = (u16*)wsb;                           wsb += EE * 2;
    int* sidx = (int*)wsb;                          wsb += 3 * BDIM * NTOK * 4;
    float* abC = (float*)wsb;                       // +BNE*4 if ws permits
    size_t need3 = (size_t)(wsb - (char*)d_ws) + BNE * 4;
    bool merged = (ws_size >= need3);

    // prep: sort (6) + x-split (8192) + weff4 (16384) in one launch
    prep_kernel<<<24582, 256, 0, stream>>>(
        x, xh, xl, wbc, wbm, wbf, sidx,
        Wq, Aq, Bq, Wk, Ak, Bk, Wv, Av, Bv, Wo, Ao, Bo,
        wh_all + 0 * EE, wl_all + 0 * EE,
        wh_all + 1 * EE, wl_all + 1 * EE,
        wh_all + 2 * EE, wl_all + 2 * EE,
        woh, wol);

    // QKV projections in one launch: V (256 blocks) + QK (512 blocks)
    gemm_qkv_kernel<<<768, 512, 0, stream>>>(
        xh, xl, wh_all, wl_all, wh_all + 2 * EE,
        bq, bk, bv, qh, ql, kh, kl, vh);

    if (merged) {
        // all 3 scales CONCURRENT: each stores to its own f32 buffer.
        float* abB = (float*)xh;
        dim3 ga3(NTOK / 128, BDIM * HEADS, 3);     // 3072 blocks
        attn_mfma_kernel<0><<<ga3, 256, 0, stream>>>(
            qh, ql, kh, kl, vh, sidx, 0, ab, abB, abC, nullptr, nullptr);
        // (abA + abB) + abC -> hi/lo split into qh/ql (free after attn)
        sumsplit3_kernel<<<BNE / 1024, 256, 0, stream>>>(ab, abB, abC, qh, ql);
        gemm_o_kernel<<<256, 512, 0, stream>>>(qh, ql, woh, wol, bo, (float*)d_out);
    } else {
        // serial fallback: store / acc / acc+split
        dim3 ga(NTOK / 128, BDIM * HEADS);
        attn_mfma_kernel<0><<<ga, 256, 0, stream>>>(
            qh, ql, kh, kl, vh, sidx, 0, ab, ab, ab, nullptr, nullptr);
        attn_mfma_kernel<1><<<ga, 256, 0, stream>>>(
            qh, ql, kh, kl, vh, sidx, 1, ab, ab, ab, nullptr, nullptr);
        attn_mfma_kernel<2><<<ga, 256, 0, stream>>>(
            qh, ql, kh, kl, vh, sidx, 2, ab, ab, ab, xh, xl);
        gemm_o_kernel<<<256, 512, 0, stream>>>(xh, xl, woh, wol, bo, (float*)d_out);
    }
}